// Round 12
// baseline (606.268 us; speedup 1.0000x reference)
//
#include <hip/hip_runtime.h>

// ---- problem constants ----
static constexpr int kN = 64;    // nodes
static constexpr int kD = 1024;  // feature dim
static constexpr int kE = 1024;  // edges (16 per row, row-major by (i,j))
static constexpr int kT = 2;     // iterations

typedef short  bf16x8 __attribute__((ext_vector_type(8)));
typedef float  f32x4  __attribute__((ext_vector_type(4)));
typedef unsigned short us8 __attribute__((ext_vector_type(8)));
typedef unsigned short us4 __attribute__((ext_vector_type(4)));

__device__ __forceinline__ unsigned short f2b(float f) {
    unsigned int u = __builtin_bit_cast(unsigned int, f);
    u += 0x7FFFu + ((u >> 16) & 1u);          // RNE
    return (unsigned short)(u >> 16);
}
__device__ __forceinline__ float b2f(unsigned short u) {
    unsigned int x = ((unsigned int)u) << 16;
    return __builtin_bit_cast(float, x);
}
__device__ __forceinline__ bf16x8 cvt8(float4 a, float4 b) {
    us8 o;
    o[0] = f2b(a.x); o[1] = f2b(a.y); o[2] = f2b(a.z); o[3] = f2b(a.w);
    o[4] = f2b(b.x); o[5] = f2b(b.y); o[6] = f2b(b.z); o[7] = f2b(b.w);
    return __builtin_bit_cast(bf16x8, o);
}

// A-operand source, bf16 [row][1024] segments:
// mode 1: concat of segments s0|s1|s2 ; mode 2: [s0 | s0*s1]
struct ASrc { const unsigned short* s0; const unsigned short* s1; const unsigned short* s2; int mode; };

__device__ __forceinline__ bf16x8 loadA8(const ASrc& s, int row, int kg) {
    const int seg = kg >> 10, k = kg & 1023;
    const size_t ro = (size_t)row * 1024 + k;
    if (s.mode == 1) {
        const unsigned short* p = (seg == 0) ? s.s0 : (seg == 1 ? s.s1 : s.s2);
        return *(const bf16x8*)(p + ro);
    }
    const bf16x8 a = *(const bf16x8*)(s.s0 + ro);
    if (seg == 0) return a;
    const bf16x8 b = *(const bf16x8*)(s.s1 + ro);
    const us8 ua = __builtin_bit_cast(us8, a), ub = __builtin_bit_cast(us8, b);
    us8 o;
#pragma unroll
    for (int q = 0; q < 8; ++q) o[q] = f2b(b2f(ua[q]) * b2f(ub[q]));
    return __builtin_bit_cast(bf16x8, o);
}

// =====================================================================
// Job-list MFMA GEMM: 64-row x 128-col tile, 4 waves (2x2), BK=64.
// A+B via swizzled LDS. pbf: bf16 partials (LDS-coalesced); else f32.
// Row-tile fastest -> XCD-affine A reuse.
// TAIL-REDUCE (split-K fixup): last z-block per output tile sums the KS
// planes (+addb bf16)(+bias), writes final Cf (f32) and/or Cb (bf16).
// Device-scope atomic counter + threadfence release/acquire.
// =====================================================================
struct GEpi { float* Cf; unsigned short* Cb; const unsigned short* addb;
              const float* bias; int tail; int cbase; };
struct GJob { ASrc a; const unsigned short* W; int ldw; void* P; int M; int K; int KS; int pbf;
              GEpi e; };
struct GJobs { GJob j[6]; int t0[7]; int nj; int* cnt; };

__global__ __launch_bounds__(256)
void k_gemm(GJobs G)
{
    __shared__ unsigned short lds[12288];   // As[64][64] | Bs[128][64]; epi Cs[64][132]
    __shared__ int lastFlag;
    const int flat = blockIdx.x;
    int ji = 0;
    while (ji + 1 < G.nj && flat >= G.t0[ji + 1]) ++ji;
    const GJob J = G.j[ji];
    const int local = flat - G.t0[ji];
    const int rowTiles = J.M >> 6;
    const int rt = local & (rowTiles - 1);          // fastest -> XCD affinity
    const int rest = local / rowTiles;
    const int ct = rest & 7, z = rest >> 3;
    const int rowBase = rt * 64, colBase = ct * 128;
    const int kchunk = J.K / J.KS, kbeg = z * kchunk, kend = kbeg + kchunk;

    const int tid = threadIdx.x, lane = tid & 63, wid = tid >> 6;
    const int l15 = lane & 15, l4 = lane >> 4;
    const int sr = tid >> 3, sc8 = tid & 7;
    const int wc8 = (sc8 ^ (sr & 7)) * 8;
    const int wr = wid >> 1, wc = wid & 1;

    bf16x8 ra[2], rb[4];
    auto stage = [&](int kt) {
#pragma unroll
        for (int h = 0; h < 2; ++h)
            ra[h] = loadA8(J.a, rowBase + sr + 32 * h, kt + sc8 * 8);
#pragma unroll
        for (int h = 0; h < 4; ++h)
            rb[h] = *(const bf16x8*)(J.W + (size_t)(colBase + sr + 32 * h) * J.ldw + kt + sc8 * 8);
    };

    f32x4 acc[2][4] = {};
    stage(kbeg);
    for (int kt = kbeg; kt < kend; kt += 64) {
        __syncthreads();
#pragma unroll
        for (int h = 0; h < 2; ++h)
            *(bf16x8*)&lds[(sr + 32 * h) * 64 + wc8] = ra[h];
#pragma unroll
        for (int h = 0; h < 4; ++h)
            *(bf16x8*)&lds[4096 + (sr + 32 * h) * 64 + wc8] = rb[h];
        __syncthreads();
        if (kt + 64 < kend) stage(kt + 64);
#pragma unroll
        for (int kk = 0; kk < 2; ++kk) {
            const int c8 = kk * 4 + l4;
            bf16x8 af[2], bv[4];
#pragma unroll
            for (int m = 0; m < 2; ++m) {
                const int ar = wr * 32 + m * 16 + l15;
                af[m] = *(const bf16x8*)&lds[ar * 64 + (c8 ^ (ar & 7)) * 8];
            }
#pragma unroll
            for (int n = 0; n < 4; ++n) {
                const int br = wc * 64 + n * 16 + l15;
                bv[n] = *(const bf16x8*)&lds[4096 + br * 64 + (c8 ^ (br & 7)) * 8];
            }
#pragma unroll
            for (int m = 0; m < 2; ++m)
#pragma unroll
                for (int n = 0; n < 4; ++n)
                    acc[m][n] = __builtin_amdgcn_mfma_f32_16x16x32_bf16(af[m], bv[n], acc[m][n], 0, 0, 0);
        }
    }

    // ---- write this block's partial plane ----
    if (J.pbf) {
        __syncthreads();
#pragma unroll
        for (int m = 0; m < 2; ++m)
#pragma unroll
            for (int n = 0; n < 4; ++n)
#pragma unroll
                for (int r = 0; r < 4; ++r)
                    lds[(wr * 32 + m * 16 + l4 * 4 + r) * 132 + wc * 64 + n * 16 + l15] =
                        f2b(acc[m][n][r]);
        __syncthreads();
        unsigned short* Pb = (unsigned short*)J.P + (size_t)z * J.M * 1024;
#pragma unroll
        for (int c = tid; c < 1024; c += 256) {
            const int row = c >> 4, ch = c & 15;
            *(bf16x8*)(Pb + (size_t)(rowBase + row) * 1024 + colBase + ch * 8) =
                *(const bf16x8*)&lds[row * 132 + ch * 8];
        }
    } else {
        float* base = (float*)J.P + (size_t)z * J.M * 1024;
#pragma unroll
        for (int m = 0; m < 2; ++m) {
            const int row = rowBase + wr * 32 + m * 16 + l4 * 4;
#pragma unroll
            for (int n = 0; n < 4; ++n) {
                const int col = colBase + wc * 64 + n * 16 + l15;
#pragma unroll
                for (int r = 0; r < 4; ++r)
                    base[(size_t)(row + r) * 1024 + col] = acc[m][n][r];
            }
        }
    }

    // ---- split-K fixup: last block for this tile reduces it ----
    if (!J.e.tail) return;
    __syncthreads();                    // all partial stores drained (barrier semantics)
    if (tid == 0) {
        __threadfence();                // release partials device-wide
        lastFlag = (atomicAdd(&G.cnt[J.e.cbase + rt * 8 + ct], 1) == J.KS - 1);
    }
    __syncthreads();
    if (!lastFlag) return;
    __threadfence();                    // acquire: other blocks' partials

    const int rr = tid >> 2, c0 = (tid & 3) * 32;
    const int grow = rowBase + rr;
#pragma unroll
    for (int g = 0; g < 4; ++g) {
        const int col = colBase + c0 + g * 8;
        const size_t oidx = (size_t)grow * 1024 + col;
        float s[8] = {0.f, 0.f, 0.f, 0.f, 0.f, 0.f, 0.f, 0.f};
        if (J.pbf) {
            const unsigned short* Pb = (const unsigned short*)J.P;
            for (int zz = 0; zz < J.KS; ++zz) {
                const us8 v = *(const us8*)(Pb + (size_t)zz * J.M * 1024 + oidx);
#pragma unroll
                for (int q = 0; q < 8; ++q) s[q] += b2f(v[q]);
            }
        } else {
            const float* Pf = (const float*)J.P;
            for (int zz = 0; zz < J.KS; ++zz) {
                const float* p = Pf + (size_t)zz * J.M * 1024 + oidx;
                const float4 v0 = *(const float4*)p;
                const float4 v1 = *(const float4*)(p + 4);
                s[0] += v0.x; s[1] += v0.y; s[2] += v0.z; s[3] += v0.w;
                s[4] += v1.x; s[5] += v1.y; s[6] += v1.z; s[7] += v1.w;
            }
        }
        if (J.e.addb) {
            const us8 v = *(const us8*)(J.e.addb + oidx);
#pragma unroll
            for (int q = 0; q < 8; ++q) s[q] += b2f(v[q]);
        }
        if (J.e.bias) {
#pragma unroll
            for (int q = 0; q < 8; ++q) s[q] += J.e.bias[col + q];
        }
        if (J.e.Cf) {
            *(float4*)(J.e.Cf + oidx)     = make_float4(s[0], s[1], s[2], s[3]);
            *(float4*)(J.e.Cf + oidx + 4) = make_float4(s[4], s[5], s[6], s[7]);
        }
        if (J.e.Cb) {
            us8 o;
#pragma unroll
            for (int q = 0; q < 8; ++q) o[q] = f2b(s[q]);
            *(us8*)(J.e.Cb + oidx) = o;
        }
    }
}

// =====================================================================
// relj final reduce: relj = sum_z bf16planes + a_s[i_e] + a_o[j_e]
// (a_s, a_o already finalized f32). Writes f32 + bf16.
// =====================================================================
__global__ void k_relj(const unsigned short* __restrict__ P, int KS,
                       const float* __restrict__ a_s, const float* __restrict__ a_o,
                       const int* __restrict__ eidx,
                       float* __restrict__ Cf, unsigned short* __restrict__ Cb)
{
    const int i8 = blockIdx.x * 256 + threadIdx.x;   // grid = 131072/256
    float s[8] = {0.f, 0.f, 0.f, 0.f, 0.f, 0.f, 0.f, 0.f};
    for (int z = 0; z < KS; ++z) {
        const us8 v = *(const us8*)(P + (size_t)z * 1048576 + (size_t)i8 * 8);
#pragma unroll
        for (int q = 0; q < 8; ++q) s[q] += b2f(v[q]);
    }
    const int e = i8 >> 7, c8 = i8 & 127;
    const int idx = eidx[e];
    const float* as_ = a_s + (size_t)(idx >> 6) * 1024 + c8 * 8;
    const float* ao_ = a_o + (size_t)(idx & 63) * 1024 + c8 * 8;
#pragma unroll
    for (int q = 0; q < 8; ++q) s[q] += as_[q] + ao_[q];
    *(float4*)(Cf + (size_t)i8 * 8)     = make_float4(s[0], s[1], s[2], s[3]);
    *(float4*)(Cf + (size_t)i8 * 8 + 4) = make_float4(s[4], s[5], s[6], s[7]);
    us8 o;
#pragma unroll
    for (int q = 0; q < 8; ++q) o[q] = f2b(s[q]);
    *(us8*)(Cb + (size_t)i8 * 8) = o;
}

// batched f32 -> bf16 conversion (7 matrices), one launch
struct ConvBatch { const float* s[7]; unsigned short* d[7]; int beg8[7]; int total8; };
__global__ void k_f2b_batch(ConvBatch cb)
{
    int i = blockIdx.x * blockDim.x + threadIdx.x;
    if (i >= cb.total8) return;
    int k = 0;
    while (k < 6 && i >= cb.beg8[k + 1]) ++k;
    const int j = i - cb.beg8[k];
    const float4 v0 = reinterpret_cast<const float4*>(cb.s[k])[2 * j];
    const float4 v1 = reinterpret_cast<const float4*>(cb.s[k])[2 * j + 1];
    const bf16x8 o = cvt8(v0, v1);
    *(bf16x8*)(cb.d[k] + (size_t)j * 8) = o;
}

// transpose 4 f32 [1024][1024] matrices into bf16 (dst[k][o] = src[o][k])
struct T4 { const float* s[4]; unsigned short* d[4]; };
__global__ __launch_bounds__(256)
void k_transpose(T4 t4)
{
    __shared__ float tile[64][65];
    const float* __restrict__ src = t4.s[blockIdx.z];
    unsigned short* __restrict__ dst = t4.d[blockIdx.z];
    const int bx = blockIdx.x * 64, by = blockIdx.y * 64;
    const int c = threadIdx.x & 63, r0 = threadIdx.x >> 6;
#pragma unroll
    for (int h = 0; h < 16; ++h) {
        const int r = r0 * 16 + h;
        tile[r][c] = src[(size_t)(by + r) * 1024 + bx + c];
    }
    __syncthreads();
#pragma unroll
    for (int h = 0; h < 16; ++h) {
        const int kk = r0 * 16 + h;
        dst[(size_t)(bx + kk) * 1024 + by + c] = f2b(tile[c][kk]);
    }
}

// build folded joint weights from W (1024 x 4096, slices W1|W2|W3|W4):
// z=0 (rel, s=+1):  rt = W1+W4,  eff = [W2-W4 | W3]
// z=1 (vj,  s=-1):  rt = W1-W4,  eff = [W2+W4 | W3]
__global__ __launch_bounds__(256)
void k_buildW(const float* __restrict__ Wrel, const float* __restrict__ Wjnt,
              unsigned short* __restrict__ WrtRel, unsigned short* __restrict__ WeffRel,
              unsigned short* __restrict__ UrtVj, unsigned short* __restrict__ UeffVj)
{
    const int idx = blockIdx.x * 256 + threadIdx.x;     // [0, 1024*256)
    const int o = idx >> 8, j = (idx & 255) * 4;
    const float* W = blockIdx.z ? Wjnt : Wrel;
    const float sgn = blockIdx.z ? -1.f : 1.f;
    unsigned short* rt = blockIdx.z ? UrtVj : WrtRel;
    unsigned short* ef = blockIdx.z ? UeffVj : WeffRel;
    const float4 w1 = *(const float4*)(W + (size_t)o * 4096 + j);
    const float4 w2 = *(const float4*)(W + (size_t)o * 4096 + 1024 + j);
    const float4 w3 = *(const float4*)(W + (size_t)o * 4096 + 2048 + j);
    const float4 w4 = *(const float4*)(W + (size_t)o * 4096 + 3072 + j);
    us4 t;
    t.x = f2b(w1.x + sgn * w4.x); t.y = f2b(w1.y + sgn * w4.y);
    t.z = f2b(w1.z + sgn * w4.z); t.w = f2b(w1.w + sgn * w4.w);
    *(us4*)(rt + (size_t)o * 1024 + j) = t;
    t.x = f2b(w2.x - sgn * w4.x); t.y = f2b(w2.y - sgn * w4.y);
    t.z = f2b(w2.z - sgn * w4.z); t.w = f2b(w2.w - sgn * w4.w);
    *(us4*)(ef + (size_t)o * 2048 + j) = t;
    t.x = f2b(w3.x); t.y = f2b(w3.y); t.z = f2b(w3.z); t.w = f2b(w3.w);
    *(us4*)(ef + (size_t)o * 2048 + 1024 + j) = t;
}

// =====================================================================
// merged scores + softmax + weighted aggregation.
// block i<64  : s[q] = <qws[i], relj[16i+q]>/32 ; ctx1[i] = softmax-weighted sum
// block j>=64 : s[i] = <qwo[j], relj[conn[i][j]]>/32 ; ctx2[j] likewise (col)
// =====================================================================
__global__ __launch_bounds__(256)
void k_sctx(const float* __restrict__ relj, const float* __restrict__ qws,
            const float* __restrict__ qwo, const int* __restrict__ conn,
            unsigned short* __restrict__ ctx1b, unsigned short* __restrict__ ctx2b)
{
    const int bid = blockIdx.x, t = threadIdx.x;
    const float4* relj4 = reinterpret_cast<const float4*>(relj);
    __shared__ float sl[64];
    __shared__ int el[64];
    float4 acc = make_float4(0.f, 0.f, 0.f, 0.f);

    if (bid < 64) {
        const int i = bid;
        {
            const int g = t >> 4, l = t & 15;          // edge i*16+g
            const size_t e4 = (size_t)(i * 16 + g) * 256;
            const float4* q4 = reinterpret_cast<const float4*>(qws) + (size_t)i * 256;
            float v = 0.f;
#pragma unroll
            for (int q = 0; q < 16; ++q) {
                const float4 r = relj4[e4 + l + q * 16];
                const float4 a = q4[l + q * 16];
                v += a.x * r.x + a.y * r.y + a.z * r.z + a.w * r.w;
            }
            v += __shfl_xor(v, 1, 16);
            v += __shfl_xor(v, 2, 16);
            v += __shfl_xor(v, 4, 16);
            v += __shfl_xor(v, 8, 16);
            if (l == 0) sl[g] = v * 0.03125f;
        }
        __syncthreads();
        float sv[16];
        float m = -1e30f;
#pragma unroll
        for (int q = 0; q < 16; ++q) { sv[q] = sl[q]; m = fmaxf(m, sv[q]); }
        float sum = 0.f;
#pragma unroll
        for (int q = 0; q < 16; ++q) { sv[q] = expf(sv[q] - m); sum += sv[q]; }
        const float inv = 1.f / sum;
#pragma unroll
        for (int q = 0; q < 16; ++q) {
            const float w = sv[q] * inv;
            const float4 v = relj4[(size_t)(i * 16 + q) * 256 + t];
            acc.x += w * v.x; acc.y += w * v.y; acc.z += w * v.z; acc.w += w * v.w;
        }
        us4 o; o.x = f2b(acc.x); o.y = f2b(acc.y); o.z = f2b(acc.z); o.w = f2b(acc.w);
        *(us4*)(ctx1b + (size_t)i * 1024 + t * 4) = o;
    } else {
        const int j = bid - 64;
        {
            const int i = t >> 2, sub = t & 3;
            const int e = conn[i * kN + j];
            if (sub == 0) el[i] = e;
            float v = 0.f;
            if (e >= 0) {
                const size_t e4 = (size_t)e * 256;
                const float4* q4 = reinterpret_cast<const float4*>(qwo) + (size_t)j * 256;
#pragma unroll
                for (int q = 0; q < 64; ++q) {
                    const float4 r = relj4[e4 + sub + q * 4];
                    const float4 a = q4[sub + q * 4];
                    v += a.x * r.x + a.y * r.y + a.z * r.z + a.w * r.w;
                }
            }
            v += __shfl_xor(v, 1, 4);
            v += __shfl_xor(v, 2, 4);
            if (sub == 0) sl[i] = (e >= 0) ? v * 0.03125f : -1e30f;
        }
        __syncthreads();
        float m = -1e30f;
        for (int i = 0; i < 64; ++i) m = fmaxf(m, sl[i]);
        float sum = 0.f;
        float ex[64];
        for (int i = 0; i < 64; ++i) {
            ex[i] = (el[i] >= 0) ? expf(sl[i] - m) : 0.f;
            sum += ex[i];
        }
        const float inv = 1.f / sum;
        for (int i = 0; i < 64; ++i) {
            const int e = el[i];
            if (e >= 0) {
                const float w = ex[i] * inv;
                const float4 v = relj4[(size_t)e * 256 + t];
                acc.x += w * v.x; acc.y += w * v.y; acc.z += w * v.z; acc.w += w * v.w;
            }
        }
        us4 o; o.x = f2b(acc.x); o.y = f2b(acc.y); o.z = f2b(acc.z); o.w = f2b(acc.w);
        *(us4*)(ctx2b + (size_t)j * 1024 + t * 4) = o;
    }
}

// =====================================================================
extern "C" void kernel_launch(void* const* d_in, const int* in_sizes, int n_in,
                              void* d_out, int out_size, void* d_ws, size_t ws_size,
                              hipStream_t stream)
{
    const float* visual   = (const float*)d_in[0];
    const float* relvis   = (const float*)d_in[1];
    const int*   conn     = (const int*)d_in[2];
    const int*   edge_idx = (const int*)d_in[4];
    const float* W_sub    = (const float*)d_in[5];
    const float* W_obj    = (const float*)d_in[6];
    const float* W_r2s    = (const float*)d_in[7];
    const float* W_r2o    = (const float*)d_in[8];
    const float* W_joint  = (const float*)d_in[9];
    const float* W_ctx    = (const float*)d_in[10];
    const float* W_relu   = (const float*)d_in[11];  // (D,3D): Ws|Wo|Wr
    const float* W_relj   = (const float*)d_in[12];
    const float* W_relc   = (const float*)d_in[13];
    const float* W_node   = (const float*)d_in[14];
    const float* b_node   = (const float*)d_in[15];
    const float* W_factor = (const float*)d_in[16];
    (void)in_sizes; (void)n_in; (void)out_size; (void)ws_size;

    int* cnt = (int*)d_ws;                         // 2048 counters (8 KB)
    float* ws = (float*)d_ws;
    size_t off = 2048;                             // skip counter block
    auto allocF = [&](size_t n) { float* p = ws + off; off += n; return p; };
    auto allocU = [&](size_t n) { return (unsigned short*)allocF((n + 1) / 2); };

    float* partF = allocF((size_t)1024 * 1024);                // f32 partials (skinny)
    unsigned short* partB = allocU((size_t)16 * 1024 * 1024);  // bf16 partials
    float* asqw  = allocF((size_t)4 * 64 * 1024);              // a_s | a_o | qW_s | qW_o
    float* relj  = allocF((size_t)kE * kD);
    unsigned short* relvis_b = allocU((size_t)kE * kD);
    unsigned short* visual_b = allocU((size_t)kN * kD);
    unsigned short* vj_b   = allocU((size_t)kN * kD);
    unsigned short* rj_b   = allocU((size_t)kE * kD);
    unsigned short* relj_b = allocU((size_t)kE * kD);
    unsigned short* rc_bA  = allocU((size_t)kE * kD);
    unsigned short* rc_bB  = allocU((size_t)kE * kD);
    unsigned short* vctx_bA = allocU((size_t)kN * kD);
    unsigned short* vctx_bB = allocU((size_t)kN * kD);
    unsigned short* ctx1_b = allocU((size_t)kN * kD);
    unsigned short* ctx2_b = allocU((size_t)kN * kD);
    unsigned short* R0_b = allocU((size_t)kE * kD);
    unsigned short* G0_b = allocU((size_t)kN * kD);
    unsigned short* Wb_ctx    = allocU((size_t)kD * 3 * kD);
    unsigned short* Wb_relu   = allocU((size_t)kD * 3 * kD);
    unsigned short* Wb_relc   = allocU((size_t)kD * 2 * kD);
    unsigned short* Wb_node   = allocU((size_t)kD * 2 * kD);
    unsigned short* Wb_factor = allocU((size_t)kD * 2 * kD);
    unsigned short* WsubT = allocU((size_t)kD * kD);
    unsigned short* WobjT = allocU((size_t)kD * kD);
    unsigned short* Wr2sT = allocU((size_t)kD * kD);
    unsigned short* Wr2oT = allocU((size_t)kD * kD);
    unsigned short* Wc_s  = allocU((size_t)kD * kD);
    unsigned short* Wc_o  = allocU((size_t)kD * kD);
    unsigned short* WrtRel  = allocU((size_t)kD * kD);      // W1+W4
    unsigned short* WeffRel = allocU((size_t)kD * 2 * kD);  // [W2-W4 | W3]
    unsigned short* UrtVj   = allocU((size_t)kD * kD);      // U1-U4
    unsigned short* UeffVj  = allocU((size_t)kD * 2 * kD);  // [U2+U4 | U3]

    auto seg1 = [](const unsigned short* a) {
        ASrc s; s.s0 = a; s.s1 = nullptr; s.s2 = nullptr; s.mode = 1; return s;
    };
    auto seg2 = [](const unsigned short* a, const unsigned short* b) {
        ASrc s; s.s0 = a; s.s1 = b; s.s2 = nullptr; s.mode = 1; return s;
    };
    auto seg3 = [](const unsigned short* a, const unsigned short* b, const unsigned short* c) {
        ASrc s; s.s0 = a; s.s1 = b; s.s2 = c; s.mode = 1; return s;
    };
    auto prodA = [](const unsigned short* c, const unsigned short* x) {  // [c | c*x]
        ASrc s; s.s0 = c; s.s1 = x; s.s2 = nullptr; s.mode = 2; return s;
    };
    auto epi = [](float* Cf, unsigned short* Cb, const unsigned short* addb,
                  const float* bias) {
        GEpi e; e.Cf = Cf; e.Cb = Cb; e.addb = addb; e.bias = bias; e.tail = 1; e.cbase = 0;
        return e;
    };
    auto noepi = []() {
        GEpi e; e.Cf = nullptr; e.Cb = nullptr; e.addb = nullptr; e.bias = nullptr;
        e.tail = 0; e.cbase = 0; return e;
    };

    // ---- job-list launch helpers ----
    GJobs G;
    G.cnt = cnt;
    int gn = 0, gt = 0, cOff = 0;
    auto gAdd = [&](ASrc a, const unsigned short* W, int ldw, void* P, int M, int K, int KS,
                    int pbf, GEpi e) {
        if (e.tail) { e.cbase = cOff; cOff += (M >> 6) * 8; }
        G.j[gn].a = a; G.j[gn].W = W; G.j[gn].ldw = ldw; G.j[gn].P = P;
        G.j[gn].M = M; G.j[gn].K = K; G.j[gn].KS = KS; G.j[gn].pbf = pbf; G.j[gn].e = e;
        G.t0[gn] = gt; gt += KS * (M >> 6) * 8; ++gn;
    };
    auto gLaunch = [&]() {
        G.nj = gn; G.t0[gn] = gt;
        hipLaunchKernelGGL(k_gemm, dim3(gt), dim3(256), 0, stream, G);
        gn = 0; gt = 0;
    };

    // ---- zero tail counters (harness does NOT re-poison between replays) ----
    hipMemsetAsync(cnt, 0, 2048 * sizeof(int), stream);

    // ---- setup ----
    {
        ConvBatch cb;
        const float* srcs[7] = {W_ctx, W_relu, W_relc, W_node, W_factor, relvis, visual};
        unsigned short* dsts[7] = {Wb_ctx, Wb_relu, Wb_relc, Wb_node, Wb_factor, relvis_b, visual_b};
        const int nel[7] = {3 * 1024 * 1024, 3 * 1024 * 1024, 2 * 1024 * 1024,
                            2 * 1024 * 1024, 2 * 1024 * 1024, 1024 * 1024, 64 * 1024};
        int cum = 0;
        for (int k = 0; k < 7; ++k) { cb.s[k] = srcs[k]; cb.d[k] = dsts[k]; cb.beg8[k] = cum; cum += nel[k] / 8; }
        cb.total8 = cum;
        hipLaunchKernelGGL(k_f2b_batch, dim3((cum + 255) / 256), dim3(256), 0, stream, cb);
    }
    {
        T4 t4;
        t4.s[0] = W_sub; t4.d[0] = WsubT;
        t4.s[1] = W_obj; t4.d[1] = WobjT;
        t4.s[2] = W_r2s; t4.d[2] = Wr2sT;
        t4.s[3] = W_r2o; t4.d[3] = Wr2oT;
        hipLaunchKernelGGL(k_transpose, dim3(16, 16, 4), dim3(256), 0, stream, t4);
    }
    hipLaunchKernelGGL(k_buildW, dim3(1024, 1, 2), dim3(256), 0, stream,
                       W_relj, W_joint, WrtRel, WeffRel, UrtVj, UeffVj);

    const size_t PB4 = (size_t)4 * 1024 * 1024;   // bf16 elems per KS=4 M=1024 job
    // S4: Wc_s, Wc_o, R0, G0 — all tail-reduced (S5 eliminated)
    gAdd(seg1(Wr2sT), WsubT, 1024, partB,           1024, 1024, 4, 1, epi(nullptr, Wc_s, nullptr, nullptr));
    gAdd(seg1(Wr2oT), WobjT, 1024, partB + PB4,     1024, 1024, 4, 1, epi(nullptr, Wc_o, nullptr, nullptr));
    gAdd(seg1(relvis_b), WrtRel, 1024, partB + 2 * PB4, 1024, 1024, 4, 1, epi(nullptr, R0_b, nullptr, nullptr));
    gAdd(seg1(visual_b), UrtVj, 1024, partF, 64, 1024, 4, 0, epi(nullptr, G0_b, nullptr, nullptr));
    gLaunch();

    // ---- T iterations ----
    for (int t = 0; t < kT; ++t) {
        const unsigned short* vcur  = (t == 0) ? visual_b : vctx_bA;
        unsigned short*       vnext = (t == 0) ? vctx_bA : vctx_bB;
        const unsigned short* rccur = (t == 0) ? relvis_b : rc_bA;
        unsigned short*       rcnext = (t == 0) ? rc_bA : rc_bB;

        // L1: vj (skinny f32 KS=8, tail -> vj_b with G0) + rj (KS=8, tail -> rj_b with R0)
        gAdd(prodA(vcur, visual_b), UeffVj, 2048, partF, 64, 2048, 8, 0,
             epi(nullptr, vj_b, G0_b, nullptr));
        gAdd(prodA(rccur, relvis_b), WeffRel, 2048, partB, 1024, 2048, 8, 1,
             epi(nullptr, rj_b, R0_b, nullptr));
        gLaunch();

        // L3: 4 skinny tail-reduced (a_s, a_o, qW_s, qW_o) + relj partials (no tail)
        gAdd(seg1(vj_b), Wb_relu,        3072, partF,          64, 1024, 2, 0,
             epi(asqw,          nullptr, nullptr, nullptr));
        gAdd(seg1(vj_b), Wb_relu + 1024, 3072, partF + 131072, 64, 1024, 2, 0,
             epi(asqw + 65536,  nullptr, nullptr, nullptr));
        gAdd(seg1(vj_b), Wc_s,           1024, partF + 262144, 64, 1024, 2, 0,
             epi(asqw + 131072, nullptr, nullptr, nullptr));
        gAdd(seg1(vj_b), Wc_o,           1024, partF + 393216, 64, 1024, 2, 0,
             epi(asqw + 196608, nullptr, nullptr, nullptr));
        gAdd(seg1(rj_b), Wb_relu + 2048, 3072, partB, 1024, 1024, 4, 1, noepi());
        gLaunch();

        // L4: relj = sum(planes) + a_s[i] + a_o[j]  (finalized gathers)
        hipLaunchKernelGGL(k_relj, dim3(512), dim3(256), 0, stream,
                           partB, 4, asqw, asqw + 65536, edge_idx, relj, relj_b);

        // merged scores + softmax + aggregation (bf16 ctx out)
        hipLaunchKernelGGL(k_sctx, dim3(128), dim3(256), 0, stream,
                           relj, asqw + 131072, asqw + 196608, conn, ctx1_b, ctx2_b);

        // L7: vctx' (skinny, tail -> vnext) + rc' (tail -> rcnext)
        gAdd(seg3(vcur, ctx1_b, ctx2_b), Wb_ctx, 3072, partF, 64, 3072, 8, 0,
             epi(nullptr, vnext, nullptr, nullptr));
        gAdd(seg2(rccur, relj_b), Wb_relc, 2048, partB, 1024, 2048, 8, 1,
             epi(nullptr, rcnext, nullptr, nullptr));
        gLaunch();
    }

    float* rel_out = (float*)d_out;
    float* v_out   = (float*)d_out + (size_t)kE * kD;
    // F1: rel_out (KS=4, tail -> f32) + v_out (skinny KS=8, tail -> f32 + bias)
    gAdd(seg2(relvis_b, rc_bB), Wb_factor, 2048, partB, 1024, 2048, 4, 1,
         epi(rel_out, nullptr, nullptr, nullptr));
    gAdd(seg2(visual_b, vctx_bB), Wb_node, 2048, partF, 64, 2048, 8, 0,
         epi(v_out, nullptr, nullptr, b_node));
    gLaunch();
}

// Round 13
// 214.993 us; speedup vs baseline: 2.8199x; 2.8199x over previous
//
#include <hip/hip_runtime.h>

// ---- problem constants ----
static constexpr int kN = 64;    // nodes
static constexpr int kD = 1024;  // feature dim
static constexpr int kE = 1024;  // edges (16 per row, row-major by (i,j))
static constexpr int kT = 2;     // iterations

typedef short  bf16x8 __attribute__((ext_vector_type(8)));
typedef float  f32x4  __attribute__((ext_vector_type(4)));
typedef unsigned short us8 __attribute__((ext_vector_type(8)));
typedef unsigned short us4 __attribute__((ext_vector_type(4)));

__device__ __forceinline__ unsigned short f2b(float f) {
    unsigned int u = __builtin_bit_cast(unsigned int, f);
    u += 0x7FFFu + ((u >> 16) & 1u);          // RNE
    return (unsigned short)(u >> 16);
}
__device__ __forceinline__ float b2f(unsigned short u) {
    unsigned int x = ((unsigned int)u) << 16;
    return __builtin_bit_cast(float, x);
}
__device__ __forceinline__ bf16x8 cvt8(float4 a, float4 b) {
    us8 o;
    o[0] = f2b(a.x); o[1] = f2b(a.y); o[2] = f2b(a.z); o[3] = f2b(a.w);
    o[4] = f2b(b.x); o[5] = f2b(b.y); o[6] = f2b(b.z); o[7] = f2b(b.w);
    return __builtin_bit_cast(bf16x8, o);
}

// A-operand source, ALL bf16 [row][1024] segments:
// mode 1: concat of segments s0|s1|s2 ; mode 2: [s0 | s0*s1]
struct ASrc { const unsigned short* s0; const unsigned short* s1; const unsigned short* s2; int mode; };

__device__ __forceinline__ bf16x8 loadA8(const ASrc& s, int row, int kg) {
    const int seg = kg >> 10, k = kg & 1023;
    const size_t ro = (size_t)row * 1024 + k;
    if (s.mode == 1) {
        const unsigned short* p = (seg == 0) ? s.s0 : (seg == 1 ? s.s1 : s.s2);
        return *(const bf16x8*)(p + ro);
    }
    const bf16x8 a = *(const bf16x8*)(s.s0 + ro);
    if (seg == 0) return a;
    const bf16x8 b = *(const bf16x8*)(s.s1 + ro);
    const us8 ua = __builtin_bit_cast(us8, a), ub = __builtin_bit_cast(us8, b);
    us8 o;
#pragma unroll
    for (int q = 0; q < 8; ++q) o[q] = f2b(b2f(ua[q]) * b2f(ub[q]));
    return __builtin_bit_cast(bf16x8, o);
}

// =====================================================================
// Job-list MFMA GEMM: uniform 64-row x 128-col tile, 4 waves (2x2), BK=64.
// A+B staged via swizzled LDS. pbf: bf16 partials via LDS-coalesced
// epilogue; else f32 direct. Row-tile fastest -> XCD-affine A reuse.
// NO device-scope fences (R12 lesson: __threadfence costs ~100us at scale).
// =====================================================================
struct GJob { ASrc a; const unsigned short* W; int ldw; void* P; int M; int K; int KS; int pbf; };
struct GJobs { GJob j[6]; int t0[7]; int nj; };

__global__ __launch_bounds__(256)
void k_gemm(GJobs G)
{
    __shared__ unsigned short lds[12288];   // As[64][64] | Bs[128][64]; epi Cs[64][132]
    const int flat = blockIdx.x;
    int ji = 0;
    while (ji + 1 < G.nj && flat >= G.t0[ji + 1]) ++ji;
    const GJob J = G.j[ji];
    const int local = flat - G.t0[ji];
    const int rowTiles = J.M >> 6;
    const int rt = local & (rowTiles - 1);          // fastest -> XCD affinity
    const int rest = local / rowTiles;
    const int ct = rest & 7, z = rest >> 3;
    const int rowBase = rt * 64, colBase = ct * 128;
    const int kchunk = J.K / J.KS, kbeg = z * kchunk, kend = kbeg + kchunk;

    const int tid = threadIdx.x, lane = tid & 63, wid = tid >> 6;
    const int l15 = lane & 15, l4 = lane >> 4;
    const int sr = tid >> 3, sc8 = tid & 7;
    const int wc8 = (sc8 ^ (sr & 7)) * 8;
    const int wr = wid >> 1, wc = wid & 1;

    bf16x8 ra[2], rb[4];
    auto stage = [&](int kt) {
#pragma unroll
        for (int h = 0; h < 2; ++h)
            ra[h] = loadA8(J.a, rowBase + sr + 32 * h, kt + sc8 * 8);
#pragma unroll
        for (int h = 0; h < 4; ++h)
            rb[h] = *(const bf16x8*)(J.W + (size_t)(colBase + sr + 32 * h) * J.ldw + kt + sc8 * 8);
    };

    f32x4 acc[2][4] = {};
    stage(kbeg);
    for (int kt = kbeg; kt < kend; kt += 64) {
        __syncthreads();
#pragma unroll
        for (int h = 0; h < 2; ++h)
            *(bf16x8*)&lds[(sr + 32 * h) * 64 + wc8] = ra[h];
#pragma unroll
        for (int h = 0; h < 4; ++h)
            *(bf16x8*)&lds[4096 + (sr + 32 * h) * 64 + wc8] = rb[h];
        __syncthreads();
        if (kt + 64 < kend) stage(kt + 64);
#pragma unroll
        for (int kk = 0; kk < 2; ++kk) {
            const int c8 = kk * 4 + l4;
            bf16x8 af[2], bv[4];
#pragma unroll
            for (int m = 0; m < 2; ++m) {
                const int ar = wr * 32 + m * 16 + l15;
                af[m] = *(const bf16x8*)&lds[ar * 64 + (c8 ^ (ar & 7)) * 8];
            }
#pragma unroll
            for (int n = 0; n < 4; ++n) {
                const int br = wc * 64 + n * 16 + l15;
                bv[n] = *(const bf16x8*)&lds[4096 + br * 64 + (c8 ^ (br & 7)) * 8];
            }
#pragma unroll
            for (int m = 0; m < 2; ++m)
#pragma unroll
                for (int n = 0; n < 4; ++n)
                    acc[m][n] = __builtin_amdgcn_mfma_f32_16x16x32_bf16(af[m], bv[n], acc[m][n], 0, 0, 0);
        }
    }

    if (J.pbf) {
        __syncthreads();
#pragma unroll
        for (int m = 0; m < 2; ++m)
#pragma unroll
            for (int n = 0; n < 4; ++n)
#pragma unroll
                for (int r = 0; r < 4; ++r)
                    lds[(wr * 32 + m * 16 + l4 * 4 + r) * 132 + wc * 64 + n * 16 + l15] =
                        f2b(acc[m][n][r]);
        __syncthreads();
        unsigned short* Pb = (unsigned short*)J.P + (size_t)z * J.M * 1024;
#pragma unroll
        for (int c = tid; c < 1024; c += 256) {
            const int row = c >> 4, ch = c & 15;
            *(bf16x8*)(Pb + (size_t)(rowBase + row) * 1024 + colBase + ch * 8) =
                *(const bf16x8*)&lds[row * 132 + ch * 8];
        }
    } else {
        float* base = (float*)J.P + (size_t)z * J.M * 1024;
#pragma unroll
        for (int m = 0; m < 2; ++m) {
            const int row = rowBase + wr * 32 + m * 16 + l4 * 4;
#pragma unroll
            for (int n = 0; n < 4; ++n) {
                const int col = colBase + wc * 64 + n * 16 + l15;
#pragma unroll
                for (int r = 0; r < 4; ++r)
                    base[(size_t)(row + r) * 1024 + col] = acc[m][n][r];
            }
        }
    }
}

// =====================================================================
// Job-list split-K reduce, 8-elem granularity.
// out = sum planes of P (KS, pbf) [+ planes of P2 (KS2, pbf2)]
//       (+addb bf16) (+bias) (+gather a_s/a_o from f32 partials at gP)
// =====================================================================
struct RJob { const void* P; int MO8; int KS; int pbf;
              const void* P2; int KS2; int pbf2;
              float* Cf; unsigned short* Cb;
              const unsigned short* addb; const float* bias; int gather; };
struct RJobs { RJob j[6]; int t0[7]; int nj; const int* eidx; const float* gP; int gKS; };

__global__ void k_reduce(RJobs R)
{
    const int flat = blockIdx.x;
    int ji = 0;
    while (ji + 1 < R.nj && flat >= R.t0[ji + 1]) ++ji;
    const RJob J = R.j[ji];
    const int i8 = (flat - R.t0[ji]) * 256 + threadIdx.x;
    if (i8 >= J.MO8) return;
    float s[8] = {0.f, 0.f, 0.f, 0.f, 0.f, 0.f, 0.f, 0.f};
    if (J.pbf) {
        const unsigned short* P = (const unsigned short*)J.P;
        for (int z = 0; z < J.KS; ++z) {
            const us8 v = *(const us8*)(P + (size_t)z * J.MO8 * 8 + (size_t)i8 * 8);
#pragma unroll
            for (int q = 0; q < 8; ++q) s[q] += b2f(v[q]);
        }
    } else {
        const float* P = (const float*)J.P;
        for (int z = 0; z < J.KS; ++z) {
            const float* p = P + (size_t)z * J.MO8 * 8 + (size_t)i8 * 8;
            const float4 v0 = *(const float4*)p;
            const float4 v1 = *(const float4*)(p + 4);
            s[0] += v0.x; s[1] += v0.y; s[2] += v0.z; s[3] += v0.w;
            s[4] += v1.x; s[5] += v1.y; s[6] += v1.z; s[7] += v1.w;
        }
    }
    if (J.P2) {
        if (J.pbf2) {
            const unsigned short* P = (const unsigned short*)J.P2;
            for (int z = 0; z < J.KS2; ++z) {
                const us8 v = *(const us8*)(P + (size_t)z * J.MO8 * 8 + (size_t)i8 * 8);
#pragma unroll
                for (int q = 0; q < 8; ++q) s[q] += b2f(v[q]);
            }
        } else {
            const float* P = (const float*)J.P2;
            for (int z = 0; z < J.KS2; ++z) {
                const float* p = P + (size_t)z * J.MO8 * 8 + (size_t)i8 * 8;
                const float4 v0 = *(const float4*)p;
                const float4 v1 = *(const float4*)(p + 4);
                s[0] += v0.x; s[1] += v0.y; s[2] += v0.z; s[3] += v0.w;
                s[4] += v1.x; s[5] += v1.y; s[6] += v1.z; s[7] += v1.w;
            }
        }
    }
    if (J.addb) {
        const us8 v = *(const us8*)(J.addb + (size_t)i8 * 8);
#pragma unroll
        for (int q = 0; q < 8; ++q) s[q] += b2f(v[q]);
    }
    if (J.gather) {
        const int e = i8 >> 7, c8 = i8 & 127;
        const int idx = R.eidx[e];
        const float* as_ = R.gP + (size_t)(idx >> 6) * 1024 + c8 * 8;
        const float* ao_ = R.gP + 131072 + (size_t)(idx & 63) * 1024 + c8 * 8;
        for (int z = 0; z < R.gKS; ++z) {
#pragma unroll
            for (int q = 0; q < 8; ++q)
                s[q] += as_[(size_t)z * 65536 + q] + ao_[(size_t)z * 65536 + q];
        }
    }
    if (J.bias) {
        const int c8 = i8 & 127;
#pragma unroll
        for (int q = 0; q < 8; ++q) s[q] += J.bias[c8 * 8 + q];
    }
    if (J.Cf) {
        *(float4*)(J.Cf + (size_t)i8 * 8)     = make_float4(s[0], s[1], s[2], s[3]);
        *(float4*)(J.Cf + (size_t)i8 * 8 + 4) = make_float4(s[4], s[5], s[6], s[7]);
    }
    if (J.Cb) {
        us8 o;
#pragma unroll
        for (int q = 0; q < 8; ++q) o[q] = f2b(s[q]);
        *(us8*)(J.Cb + (size_t)i8 * 8) = o;
    }
}

// batched f32 -> bf16 conversion (7 matrices), one launch
struct ConvBatch { const float* s[7]; unsigned short* d[7]; int beg8[7]; int total8; };
__global__ void k_f2b_batch(ConvBatch cb)
{
    int i = blockIdx.x * blockDim.x + threadIdx.x;
    if (i >= cb.total8) return;
    int k = 0;
    while (k < 6 && i >= cb.beg8[k + 1]) ++k;
    const int j = i - cb.beg8[k];
    const float4 v0 = reinterpret_cast<const float4*>(cb.s[k])[2 * j];
    const float4 v1 = reinterpret_cast<const float4*>(cb.s[k])[2 * j + 1];
    const bf16x8 o = cvt8(v0, v1);
    *(bf16x8*)(cb.d[k] + (size_t)j * 8) = o;
}

// transpose 4 f32 [1024][1024] matrices into bf16 (dst[k][o] = src[o][k])
struct T4 { const float* s[4]; unsigned short* d[4]; };
__global__ __launch_bounds__(256)
void k_transpose(T4 t4)
{
    __shared__ float tile[64][65];
    const float* __restrict__ src = t4.s[blockIdx.z];
    unsigned short* __restrict__ dst = t4.d[blockIdx.z];
    const int bx = blockIdx.x * 64, by = blockIdx.y * 64;
    const int c = threadIdx.x & 63, r0 = threadIdx.x >> 6;
#pragma unroll
    for (int h = 0; h < 16; ++h) {
        const int r = r0 * 16 + h;
        tile[r][c] = src[(size_t)(by + r) * 1024 + bx + c];
    }
    __syncthreads();
#pragma unroll
    for (int h = 0; h < 16; ++h) {
        const int kk = r0 * 16 + h;
        dst[(size_t)(bx + kk) * 1024 + by + c] = f2b(tile[c][kk]);
    }
}

// build folded joint weights from W (1024 x 4096, slices W1|W2|W3|W4):
// z=0 (rel, s=+1):  rt = W1+W4,  eff = [W2-W4 | W3]
// z=1 (vj,  s=-1):  rt = W1-W4,  eff = [W2+W4 | W3]
__global__ __launch_bounds__(256)
void k_buildW(const float* __restrict__ Wrel, const float* __restrict__ Wjnt,
              unsigned short* __restrict__ WrtRel, unsigned short* __restrict__ WeffRel,
              unsigned short* __restrict__ UrtVj, unsigned short* __restrict__ UeffVj)
{
    const int idx = blockIdx.x * 256 + threadIdx.x;     // [0, 1024*256)
    const int o = idx >> 8, j = (idx & 255) * 4;
    const float* W = blockIdx.z ? Wjnt : Wrel;
    const float sgn = blockIdx.z ? -1.f : 1.f;
    unsigned short* rt = blockIdx.z ? UrtVj : WrtRel;
    unsigned short* ef = blockIdx.z ? UeffVj : WeffRel;
    const float4 w1 = *(const float4*)(W + (size_t)o * 4096 + j);
    const float4 w2 = *(const float4*)(W + (size_t)o * 4096 + 1024 + j);
    const float4 w3 = *(const float4*)(W + (size_t)o * 4096 + 2048 + j);
    const float4 w4 = *(const float4*)(W + (size_t)o * 4096 + 3072 + j);
    us4 t;
    t.x = f2b(w1.x + sgn * w4.x); t.y = f2b(w1.y + sgn * w4.y);
    t.z = f2b(w1.z + sgn * w4.z); t.w = f2b(w1.w + sgn * w4.w);
    *(us4*)(rt + (size_t)o * 1024 + j) = t;
    t.x = f2b(w2.x - sgn * w4.x); t.y = f2b(w2.y - sgn * w4.y);
    t.z = f2b(w2.z - sgn * w4.z); t.w = f2b(w2.w - sgn * w4.w);
    *(us4*)(ef + (size_t)o * 2048 + j) = t;
    t.x = f2b(w3.x); t.y = f2b(w3.y); t.z = f2b(w3.z); t.w = f2b(w3.w);
    *(us4*)(ef + (size_t)o * 2048 + 1024 + j) = t;
}

// s_sbj[e] = <qW_s[i_e], relj[e]>/32 ; s_obj[e] = <qW_o[j_e], relj[e]>/32
__global__ __launch_bounds__(256)
void k_scores(const float* __restrict__ qws, const float* __restrict__ qwo,
              const float* __restrict__ relj, const int* __restrict__ eidx,
              float* __restrict__ s_sbj, float* __restrict__ s_obj)
{
    const int e = blockIdx.x, t = threadIdx.x;
    const int idx = eidx[e];
    const int i = idx >> 6, j = idx & 63;
    const float4 r = reinterpret_cast<const float4*>(relj)[(size_t)e * 256 + t];
    const float4 a = reinterpret_cast<const float4*>(qws)[(size_t)i * 256 + t];
    const float4 b = reinterpret_cast<const float4*>(qwo)[(size_t)j * 256 + t];
    float vs = a.x * r.x + a.y * r.y + a.z * r.z + a.w * r.w;
    float vo = b.x * r.x + b.y * r.y + b.z * r.z + b.w * r.w;
    for (int off = 32; off; off >>= 1) {
        vs += __shfl_down(vs, off);
        vo += __shfl_down(vo, off);
    }
    __shared__ float ss[4], so[4];
    const int w = t >> 6, lane = t & 63;
    if (lane == 0) { ss[w] = vs; so[w] = vo; }
    __syncthreads();
    if (t == 0) {
        s_sbj[e] = (ss[0] + ss[1] + ss[2] + ss[3]) * 0.03125f;
        s_obj[e] = (so[0] + so[1] + so[2] + so[3]) * 0.03125f;
    }
}

// fused softmax + weighted aggregation -> bf16 ctx outputs
__global__ __launch_bounds__(256)
void k_ctx12(const float* __restrict__ relj, const float* __restrict__ s_sbj,
             const float* __restrict__ s_obj, const int* __restrict__ conn,
             unsigned short* __restrict__ ctx1b, unsigned short* __restrict__ ctx2b)
{
    const int bid = blockIdx.x, t = threadIdx.x;
    const float4* relj4 = reinterpret_cast<const float4*>(relj);
    float4 acc = make_float4(0.f, 0.f, 0.f, 0.f);
    if (bid < 64) {
        const int i = bid;
        float sv[16];
        float m = -1e30f;
#pragma unroll
        for (int q = 0; q < 16; ++q) { sv[q] = s_sbj[i * 16 + q]; m = fmaxf(m, sv[q]); }
        float sum = 0.f;
#pragma unroll
        for (int q = 0; q < 16; ++q) { sv[q] = expf(sv[q] - m); sum += sv[q]; }
        const float inv = 1.f / sum;
#pragma unroll
        for (int q = 0; q < 16; ++q) {
            const float w = sv[q] * inv;
            const float4 v = relj4[(size_t)(i * 16 + q) * 256 + t];
            acc.x += w * v.x; acc.y += w * v.y; acc.z += w * v.z; acc.w += w * v.w;
        }
        us4 o; o.x = f2b(acc.x); o.y = f2b(acc.y); o.z = f2b(acc.z); o.w = f2b(acc.w);
        *(us4*)(ctx1b + (size_t)bid * 1024 + t * 4) = o;
    } else {
        const int j = bid - 64;
        __shared__ float sl[64];
        __shared__ int el[64];
        if (t < 64) {
            const int e = conn[t * kN + j];
            el[t] = e;
            sl[t] = (e >= 0) ? s_obj[e] : -1e30f;
        }
        __syncthreads();
        float m = -1e30f;
        for (int i = 0; i < 64; ++i) m = fmaxf(m, sl[i]);
        __syncthreads();
        if (t < 64) sl[t] = (el[t] >= 0) ? expf(sl[t] - m) : 0.f;
        __syncthreads();
        float sum = 0.f;
        for (int i = 0; i < 64; ++i) sum += sl[i];
        const float inv = 1.f / sum;
        for (int i = 0; i < 64; ++i) {
            const int e = el[i];
            if (e >= 0) {
                const float w = sl[i] * inv;
                const float4 v = relj4[(size_t)e * 256 + t];
                acc.x += w * v.x; acc.y += w * v.y; acc.z += w * v.z; acc.w += w * v.w;
            }
        }
        us4 o; o.x = f2b(acc.x); o.y = f2b(acc.y); o.z = f2b(acc.z); o.w = f2b(acc.w);
        *(us4*)(ctx2b + (size_t)j * 1024 + t * 4) = o;
    }
}

// =====================================================================
extern "C" void kernel_launch(void* const* d_in, const int* in_sizes, int n_in,
                              void* d_out, int out_size, void* d_ws, size_t ws_size,
                              hipStream_t stream)
{
    const float* visual   = (const float*)d_in[0];
    const float* relvis   = (const float*)d_in[1];
    const int*   conn     = (const int*)d_in[2];
    const int*   edge_idx = (const int*)d_in[4];
    const float* W_sub    = (const float*)d_in[5];
    const float* W_obj    = (const float*)d_in[6];
    const float* W_r2s    = (const float*)d_in[7];
    const float* W_r2o    = (const float*)d_in[8];
    const float* W_joint  = (const float*)d_in[9];
    const float* W_ctx    = (const float*)d_in[10];
    const float* W_relu   = (const float*)d_in[11];  // (D,3D): Ws|Wo|Wr
    const float* W_relj   = (const float*)d_in[12];
    const float* W_relc   = (const float*)d_in[13];
    const float* W_node   = (const float*)d_in[14];
    const float* b_node   = (const float*)d_in[15];
    const float* W_factor = (const float*)d_in[16];
    (void)in_sizes; (void)n_in; (void)out_size; (void)ws_size;

    float* ws = (float*)d_ws;
    size_t off = 0;
    auto allocF = [&](size_t n) { float* p = ws + off; off += n; return p; };
    auto allocU = [&](size_t n) { return (unsigned short*)allocF((n + 1) / 2); };

    float* partF = allocF((size_t)1024 * 1024);                // f32 partials (skinny)
    unsigned short* partB = allocU((size_t)16 * 1024 * 1024);  // bf16 partials
    float* G0p  = allocF((size_t)4 * 65536);                   // G0 f32 planes (persist)
    unsigned short* R0p = allocU((size_t)4 * 1024 * 1024);     // R0 bf16 planes (persist)
    float* asqw  = allocF((size_t)4 * 64 * 1024);              // a_s | a_o | qW_s | qW_o
    float* relj  = allocF((size_t)kE * kD);
    float* s_sbj = allocF(kE);
    float* s_obj = allocF(kE);
    unsigned short* relvis_b = allocU((size_t)kE * kD);
    unsigned short* visual_b = allocU((size_t)kN * kD);
    unsigned short* vj_b   = allocU((size_t)kN * kD);
    unsigned short* rj_b   = allocU((size_t)kE * kD);
    unsigned short* relj_b = allocU((size_t)kE * kD);
    unsigned short* rc_bA  = allocU((size_t)kE * kD);
    unsigned short* rc_bB  = allocU((size_t)kE * kD);
    unsigned short* vctx_bA = allocU((size_t)kN * kD);
    unsigned short* vctx_bB = allocU((size_t)kN * kD);
    unsigned short* ctx1_b = allocU((size_t)kN * kD);
    unsigned short* ctx2_b = allocU((size_t)kN * kD);
    unsigned short* Wb_ctx    = allocU((size_t)kD * 3 * kD);
    unsigned short* Wb_relu   = allocU((size_t)kD * 3 * kD);
    unsigned short* Wb_relc   = allocU((size_t)kD * 2 * kD);
    unsigned short* Wb_node   = allocU((size_t)kD * 2 * kD);
    unsigned short* Wb_factor = allocU((size_t)kD * 2 * kD);
    unsigned short* WsubT = allocU((size_t)kD * kD);
    unsigned short* WobjT = allocU((size_t)kD * kD);
    unsigned short* Wr2sT = allocU((size_t)kD * kD);
    unsigned short* Wr2oT = allocU((size_t)kD * kD);
    unsigned short* Wc_s  = allocU((size_t)kD * kD);
    unsigned short* Wc_o  = allocU((size_t)kD * kD);
    unsigned short* WrtRel  = allocU((size_t)kD * kD);      // W1+W4
    unsigned short* WeffRel = allocU((size_t)kD * 2 * kD);  // [W2-W4 | W3]
    unsigned short* UrtVj   = allocU((size_t)kD * kD);      // U1-U4
    unsigned short* UeffVj  = allocU((size_t)kD * 2 * kD);  // [U2+U4 | U3]

    auto seg1 = [](const unsigned short* a) {
        ASrc s; s.s0 = a; s.s1 = nullptr; s.s2 = nullptr; s.mode = 1; return s;
    };
    auto seg2 = [](const unsigned short* a, const unsigned short* b) {
        ASrc s; s.s0 = a; s.s1 = b; s.s2 = nullptr; s.mode = 1; return s;
    };
    auto seg3 = [](const unsigned short* a, const unsigned short* b, const unsigned short* c) {
        ASrc s; s.s0 = a; s.s1 = b; s.s2 = c; s.mode = 1; return s;
    };
    auto prodA = [](const unsigned short* c, const unsigned short* x) {  // [c | c*x]
        ASrc s; s.s0 = c; s.s1 = x; s.s2 = nullptr; s.mode = 2; return s;
    };

    // ---- job-list launch helpers ----
    GJobs G; RJobs R;
    int gn = 0, gt = 0, rn = 0, rtt = 0;
    auto gAdd = [&](ASrc a, const unsigned short* W, int ldw, void* P, int M, int K, int KS, int pbf) {
        G.j[gn].a = a; G.j[gn].W = W; G.j[gn].ldw = ldw; G.j[gn].P = P;
        G.j[gn].M = M; G.j[gn].K = K; G.j[gn].KS = KS; G.j[gn].pbf = pbf;
        G.t0[gn] = gt; gt += KS * (M >> 6) * 8; ++gn;
    };
    auto gLaunch = [&]() {
        G.nj = gn; G.t0[gn] = gt;
        hipLaunchKernelGGL(k_gemm, dim3(gt), dim3(256), 0, stream, G);
        gn = 0; gt = 0;
    };
    auto rAdd = [&](const void* P, int MO8, int KS, int pbf,
                    const void* P2, int KS2, int pbf2,
                    float* Cf, unsigned short* Cb,
                    const unsigned short* addb, const float* bias, int gather) {
        R.j[rn].P = P; R.j[rn].MO8 = MO8; R.j[rn].KS = KS; R.j[rn].pbf = pbf;
        R.j[rn].P2 = P2; R.j[rn].KS2 = KS2; R.j[rn].pbf2 = pbf2;
        R.j[rn].Cf = Cf; R.j[rn].Cb = Cb; R.j[rn].addb = addb; R.j[rn].bias = bias;
        R.j[rn].gather = gather;
        R.t0[rn] = rtt; rtt += (MO8 + 255) / 256; ++rn;
    };
    auto rLaunch = [&](const int* eidx, const float* gP, int gKS) {
        R.nj = rn; R.t0[rn] = rtt; R.eidx = eidx; R.gP = gP; R.gKS = gKS;
        hipLaunchKernelGGL(k_reduce, dim3(rtt), dim3(256), 0, stream, R);
        rn = 0; rtt = 0;
    };

    // ---- setup (3 launches; setup GEMMs folded into iter-0 L1/L2) ----
    {
        ConvBatch cb;
        const float* srcs[7] = {W_ctx, W_relu, W_relc, W_node, W_factor, relvis, visual};
        unsigned short* dsts[7] = {Wb_ctx, Wb_relu, Wb_relc, Wb_node, Wb_factor, relvis_b, visual_b};
        const int nel[7] = {3 * 1024 * 1024, 3 * 1024 * 1024, 2 * 1024 * 1024,
                            2 * 1024 * 1024, 2 * 1024 * 1024, 1024 * 1024, 64 * 1024};
        int cum = 0;
        for (int k = 0; k < 7; ++k) { cb.s[k] = srcs[k]; cb.d[k] = dsts[k]; cb.beg8[k] = cum; cum += nel[k] / 8; }
        cb.total8 = cum;
        hipLaunchKernelGGL(k_f2b_batch, dim3((cum + 255) / 256), dim3(256), 0, stream, cb);
    }
    {
        T4 t4;
        t4.s[0] = W_sub; t4.d[0] = WsubT;
        t4.s[1] = W_obj; t4.d[1] = WobjT;
        t4.s[2] = W_r2s; t4.d[2] = Wr2sT;
        t4.s[3] = W_r2o; t4.d[3] = Wr2oT;
        hipLaunchKernelGGL(k_transpose, dim3(16, 16, 4), dim3(256), 0, stream, t4);
    }
    hipLaunchKernelGGL(k_buildW, dim3(1024, 1, 2), dim3(256), 0, stream,
                       W_relj, W_joint, WrtRel, WeffRel, UrtVj, UeffVj);

    const size_t M8 = (size_t)8 * 1024 * 1024;    // bf16 elems
    const size_t M12 = (size_t)12 * 1024 * 1024;

    // ---- T iterations ----
    for (int t = 0; t < kT; ++t) {
        const unsigned short* vcur  = (t == 0) ? visual_b : vctx_bA;
        unsigned short*       vnext = (t == 0) ? vctx_bA : vctx_bB;
        const unsigned short* rccur = (t == 0) ? relvis_b : rc_bA;
        unsigned short*       rcnext = (t == 0) ? rc_bA : rc_bB;

        // L1: vj (f32 KS=8) + rj (bf16 KS=8); iter0 adds Wc_s, Wc_o, R0, G0
        gAdd(prodA(vcur, visual_b), UeffVj, 2048, partF, 64, 2048, 8, 0);
        gAdd(prodA(rccur, relvis_b), WeffRel, 2048, partB, 1024, 2048, 8, 1);
        if (t == 0) {
            gAdd(seg1(Wr2sT), WsubT, 1024, partB + M8,  1024, 1024, 4, 1);   // Wc_s planes
            gAdd(seg1(Wr2oT), WobjT, 1024, partB + M12, 1024, 1024, 4, 1);   // Wc_o planes
            gAdd(seg1(relvis_b), WrtRel, 1024, R0p, 1024, 1024, 4, 1);       // R0 planes
            gAdd(seg1(visual_b), UrtVj, 1024, G0p, 64, 1024, 4, 0);          // G0 planes
        }
        gLaunch();
        // L2: vj = sum(vj planes) + sum(G0 planes) -> bf16
        //     rj = sum(rj planes) + sum(R0 planes) -> bf16 ; iter0: finalize Wc_s/Wc_o
        rAdd(partF, 8192, 8, 0, G0p, 4, 0, nullptr, vj_b, nullptr, nullptr, 0);
        rAdd(partB, 131072, 8, 1, R0p, 4, 1, nullptr, rj_b, nullptr, nullptr, 0);
        if (t == 0) {
            rAdd(partB + M8,  131072, 4, 1, nullptr, 0, 0, nullptr, Wc_s, nullptr, nullptr, 0);
            rAdd(partB + M12, 131072, 4, 1, nullptr, 0, 0, nullptr, Wc_o, nullptr, nullptr, 0);
        }
        rLaunch(nullptr, nullptr, 0);

        // L3: asqw (4 skinny, f32 KS=2) + relj (bf16 KS=4)
        gAdd(seg1(vj_b), Wb_relu,        3072, partF,          64, 1024, 2, 0);  // a_s
        gAdd(seg1(vj_b), Wb_relu + 1024, 3072, partF + 131072, 64, 1024, 2, 0);  // a_o
        gAdd(seg1(vj_b), Wc_s,           1024, partF + 262144, 64, 1024, 2, 0);  // qW_s
        gAdd(seg1(vj_b), Wc_o,           1024, partF + 393216, 64, 1024, 2, 0);  // qW_o
        gAdd(seg1(rj_b), Wb_relu + 2048, 3072, partB,        1024, 1024, 4, 1);  // relj
        gLaunch();
        // L4: asqw sums + relj (sum + gather a_s/a_o from f32 partials)
        rAdd(partF,          8192, 2, 0, nullptr, 0, 0, asqw,          nullptr, nullptr, nullptr, 0);
        rAdd(partF + 131072, 8192, 2, 0, nullptr, 0, 0, asqw + 65536,  nullptr, nullptr, nullptr, 0);
        rAdd(partF + 262144, 8192, 2, 0, nullptr, 0, 0, asqw + 131072, nullptr, nullptr, nullptr, 0);
        rAdd(partF + 393216, 8192, 2, 0, nullptr, 0, 0, asqw + 196608, nullptr, nullptr, nullptr, 0);
        rAdd(partB, 131072, 4, 1, nullptr, 0, 0, relj, relj_b, nullptr, nullptr, 1);
        rLaunch(edge_idx, partF, 2);

        // scores + softmax/aggregate (bf16 ctx out)
        hipLaunchKernelGGL(k_scores, dim3(kE), dim3(256), 0, stream,
                           asqw + 131072, asqw + 196608, relj, edge_idx, s_sbj, s_obj);
        hipLaunchKernelGGL(k_ctx12, dim3(128), dim3(256), 0, stream,
                           relj, s_sbj, s_obj, conn, ctx1_b, ctx2_b);

        // L7: vctx' + rc'
        gAdd(seg3(vcur, ctx1_b, ctx2_b), Wb_ctx, 3072, partF, 64, 3072, 8, 0);
        gAdd(seg2(rccur, relj_b), Wb_relc, 2048, partB, 1024, 2048, 8, 1);
        gLaunch();
        // L8
        rAdd(partF, 8192, 8, 0, nullptr, 0, 0, nullptr, vnext, nullptr, nullptr, 0);
        rAdd(partB, 131072, 8, 1, nullptr, 0, 0, nullptr, rcnext, nullptr, nullptr, 0);
        rLaunch(nullptr, nullptr, 0);
    }

    float* rel_out = (float*)d_out;
    float* v_out   = (float*)d_out + (size_t)kE * kD;
    // F1: rel_out (bf16 partials KS=4) + v_out (f32 partials KS=8, skinny)
    gAdd(seg2(relvis_b, rc_bB), Wb_factor, 2048, partB, 1024, 2048, 4, 1);
    gAdd(seg2(visual_b, vctx_bB), Wb_node, 2048, partF, 64, 2048, 8, 0);
    gLaunch();
    // F2
    rAdd(partB, 131072, 4, 1, nullptr, 0, 0, rel_out, nullptr, nullptr, nullptr, 0);
    rAdd(partF, 8192, 8, 0, nullptr, 0, 0, v_out, nullptr, nullptr, b_node, 0);
    rLaunch(nullptr, nullptr, 0);
}

// Round 14
// 208.397 us; speedup vs baseline: 2.9092x; 1.0316x over previous
//
#include <hip/hip_runtime.h>

// ---- problem constants ----
static constexpr int kN = 64;    // nodes
static constexpr int kD = 1024;  // feature dim
static constexpr int kE = 1024;  // edges (16 per row, row-major by (i,j))
static constexpr int kT = 2;     // iterations

typedef short  bf16x8 __attribute__((ext_vector_type(8)));
typedef float  f32x4  __attribute__((ext_vector_type(4)));
typedef unsigned short us8 __attribute__((ext_vector_type(8)));
typedef unsigned short us4 __attribute__((ext_vector_type(4)));

__device__ __forceinline__ unsigned short f2b(float f) {
    unsigned int u = __builtin_bit_cast(unsigned int, f);
    u += 0x7FFFu + ((u >> 16) & 1u);          // RNE
    return (unsigned short)(u >> 16);
}
__device__ __forceinline__ float b2f(unsigned short u) {
    unsigned int x = ((unsigned int)u) << 16;
    return __builtin_bit_cast(float, x);
}
__device__ __forceinline__ bf16x8 cvt8(float4 a, float4 b) {
    us8 o;
    o[0] = f2b(a.x); o[1] = f2b(a.y); o[2] = f2b(a.z); o[3] = f2b(a.w);
    o[4] = f2b(b.x); o[5] = f2b(b.y); o[6] = f2b(b.z); o[7] = f2b(b.w);
    return __builtin_bit_cast(bf16x8, o);
}

// A-operand source, ALL bf16 [row][1024] segments:
// mode 1: concat of segments s0|s1|s2 ; mode 2: [s0 | s0*s1]
struct ASrc { const unsigned short* s0; const unsigned short* s1; const unsigned short* s2; int mode; };

__device__ __forceinline__ bf16x8 loadA8(const ASrc& s, int row, int kg) {
    const int seg = kg >> 10, k = kg & 1023;
    const size_t ro = (size_t)row * 1024 + k;
    if (s.mode == 1) {
        const unsigned short* p = (seg == 0) ? s.s0 : (seg == 1 ? s.s1 : s.s2);
        return *(const bf16x8*)(p + ro);
    }
    const bf16x8 a = *(const bf16x8*)(s.s0 + ro);
    if (seg == 0) return a;
    const bf16x8 b = *(const bf16x8*)(s.s1 + ro);
    const us8 ua = __builtin_bit_cast(us8, a), ub = __builtin_bit_cast(us8, b);
    us8 o;
#pragma unroll
    for (int q = 0; q < 8; ++q) o[q] = f2b(b2f(ua[q]) * b2f(ub[q]));
    return __builtin_bit_cast(bf16x8, o);
}

// =====================================================================
// Job-list MFMA GEMM: uniform 64-row x 128-col tile, 4 waves (2x2), BK=64.
// A+B staged via swizzled LDS. pbf: bf16 partials via LDS-coalesced
// epilogue; else f32 direct. Row-tile fastest -> XCD-affine A reuse.
// NO device-scope fences (R12 lesson: __threadfence costs ~100us at scale).
// =====================================================================
struct GJob { ASrc a; const unsigned short* W; int ldw; void* P; int M; int K; int KS; int pbf; };
struct GJobs { GJob j[6]; int t0[7]; int nj; };

__global__ __launch_bounds__(256)
void k_gemm(GJobs G)
{
    __shared__ unsigned short lds[12288];   // As[64][64] | Bs[128][64]; epi Cs[64][132]
    const int flat = blockIdx.x;
    int ji = 0;
    while (ji + 1 < G.nj && flat >= G.t0[ji + 1]) ++ji;
    const GJob J = G.j[ji];
    const int local = flat - G.t0[ji];
    const int rowTiles = J.M >> 6;
    const int rt = local & (rowTiles - 1);          // fastest -> XCD affinity
    const int rest = local / rowTiles;
    const int ct = rest & 7, z = rest >> 3;
    const int rowBase = rt * 64, colBase = ct * 128;
    const int kchunk = J.K / J.KS, kbeg = z * kchunk, kend = kbeg + kchunk;

    const int tid = threadIdx.x, lane = tid & 63, wid = tid >> 6;
    const int l15 = lane & 15, l4 = lane >> 4;
    const int sr = tid >> 3, sc8 = tid & 7;
    const int wc8 = (sc8 ^ (sr & 7)) * 8;
    const int wr = wid >> 1, wc = wid & 1;

    bf16x8 ra[2], rb[4];
    auto stage = [&](int kt) {
#pragma unroll
        for (int h = 0; h < 2; ++h)
            ra[h] = loadA8(J.a, rowBase + sr + 32 * h, kt + sc8 * 8);
#pragma unroll
        for (int h = 0; h < 4; ++h)
            rb[h] = *(const bf16x8*)(J.W + (size_t)(colBase + sr + 32 * h) * J.ldw + kt + sc8 * 8);
    };

    f32x4 acc[2][4] = {};
    stage(kbeg);
    for (int kt = kbeg; kt < kend; kt += 64) {
        __syncthreads();
#pragma unroll
        for (int h = 0; h < 2; ++h)
            *(bf16x8*)&lds[(sr + 32 * h) * 64 + wc8] = ra[h];
#pragma unroll
        for (int h = 0; h < 4; ++h)
            *(bf16x8*)&lds[4096 + (sr + 32 * h) * 64 + wc8] = rb[h];
        __syncthreads();
        if (kt + 64 < kend) stage(kt + 64);
#pragma unroll
        for (int kk = 0; kk < 2; ++kk) {
            const int c8 = kk * 4 + l4;
            bf16x8 af[2], bv[4];
#pragma unroll
            for (int m = 0; m < 2; ++m) {
                const int ar = wr * 32 + m * 16 + l15;
                af[m] = *(const bf16x8*)&lds[ar * 64 + (c8 ^ (ar & 7)) * 8];
            }
#pragma unroll
            for (int n = 0; n < 4; ++n) {
                const int br = wc * 64 + n * 16 + l15;
                bv[n] = *(const bf16x8*)&lds[4096 + br * 64 + (c8 ^ (br & 7)) * 8];
            }
#pragma unroll
            for (int m = 0; m < 2; ++m)
#pragma unroll
                for (int n = 0; n < 4; ++n)
                    acc[m][n] = __builtin_amdgcn_mfma_f32_16x16x32_bf16(af[m], bv[n], acc[m][n], 0, 0, 0);
        }
    }

    if (J.pbf) {
        __syncthreads();
#pragma unroll
        for (int m = 0; m < 2; ++m)
#pragma unroll
            for (int n = 0; n < 4; ++n)
#pragma unroll
                for (int r = 0; r < 4; ++r)
                    lds[(wr * 32 + m * 16 + l4 * 4 + r) * 132 + wc * 64 + n * 16 + l15] =
                        f2b(acc[m][n][r]);
        __syncthreads();
        unsigned short* Pb = (unsigned short*)J.P + (size_t)z * J.M * 1024;
#pragma unroll
        for (int c = tid; c < 1024; c += 256) {
            const int row = c >> 4, ch = c & 15;
            *(bf16x8*)(Pb + (size_t)(rowBase + row) * 1024 + colBase + ch * 8) =
                *(const bf16x8*)&lds[row * 132 + ch * 8];
        }
    } else {
        float* base = (float*)J.P + (size_t)z * J.M * 1024;
#pragma unroll
        for (int m = 0; m < 2; ++m) {
            const int row = rowBase + wr * 32 + m * 16 + l4 * 4;
#pragma unroll
            for (int n = 0; n < 4; ++n) {
                const int col = colBase + wc * 64 + n * 16 + l15;
#pragma unroll
                for (int r = 0; r < 4; ++r)
                    base[(size_t)(row + r) * 1024 + col] = acc[m][n][r];
            }
        }
    }
}

// =====================================================================
// Job-list split-K reduce, 8-elem granularity.
// out = sum planes of P (KS, pbf) [+ planes of P2 (KS2, pbf2)]
//       (+addb bf16) (+bias)
// =====================================================================
struct RJob { const void* P; int MO8; int KS; int pbf;
              const void* P2; int KS2; int pbf2;
              float* Cf; unsigned short* Cb;
              const unsigned short* addb; const float* bias; };
struct RJobs { RJob j[6]; int t0[7]; int nj; };

__global__ void k_reduce(RJobs R)
{
    const int flat = blockIdx.x;
    int ji = 0;
    while (ji + 1 < R.nj && flat >= R.t0[ji + 1]) ++ji;
    const RJob J = R.j[ji];
    const int i8 = (flat - R.t0[ji]) * 256 + threadIdx.x;
    if (i8 >= J.MO8) return;
    float s[8] = {0.f, 0.f, 0.f, 0.f, 0.f, 0.f, 0.f, 0.f};
    if (J.pbf) {
        const unsigned short* P = (const unsigned short*)J.P;
        for (int z = 0; z < J.KS; ++z) {
            const us8 v = *(const us8*)(P + (size_t)z * J.MO8 * 8 + (size_t)i8 * 8);
#pragma unroll
            for (int q = 0; q < 8; ++q) s[q] += b2f(v[q]);
        }
    } else {
        const float* P = (const float*)J.P;
        for (int z = 0; z < J.KS; ++z) {
            const float* p = P + (size_t)z * J.MO8 * 8 + (size_t)i8 * 8;
            const float4 v0 = *(const float4*)p;
            const float4 v1 = *(const float4*)(p + 4);
            s[0] += v0.x; s[1] += v0.y; s[2] += v0.z; s[3] += v0.w;
            s[4] += v1.x; s[5] += v1.y; s[6] += v1.z; s[7] += v1.w;
        }
    }
    if (J.P2) {
        if (J.pbf2) {
            const unsigned short* P = (const unsigned short*)J.P2;
            for (int z = 0; z < J.KS2; ++z) {
                const us8 v = *(const us8*)(P + (size_t)z * J.MO8 * 8 + (size_t)i8 * 8);
#pragma unroll
                for (int q = 0; q < 8; ++q) s[q] += b2f(v[q]);
            }
        } else {
            const float* P = (const float*)J.P2;
            for (int z = 0; z < J.KS2; ++z) {
                const float* p = P + (size_t)z * J.MO8 * 8 + (size_t)i8 * 8;
                const float4 v0 = *(const float4*)p;
                const float4 v1 = *(const float4*)(p + 4);
                s[0] += v0.x; s[1] += v0.y; s[2] += v0.z; s[3] += v0.w;
                s[4] += v1.x; s[5] += v1.y; s[6] += v1.z; s[7] += v1.w;
            }
        }
    }
    if (J.addb) {
        const us8 v = *(const us8*)(J.addb + (size_t)i8 * 8);
#pragma unroll
        for (int q = 0; q < 8; ++q) s[q] += b2f(v[q]);
    }
    if (J.bias) {
        const int c8 = i8 & 127;
#pragma unroll
        for (int q = 0; q < 8; ++q) s[q] += J.bias[c8 * 8 + q];
    }
    if (J.Cf) {
        *(float4*)(J.Cf + (size_t)i8 * 8)     = make_float4(s[0], s[1], s[2], s[3]);
        *(float4*)(J.Cf + (size_t)i8 * 8 + 4) = make_float4(s[4], s[5], s[6], s[7]);
    }
    if (J.Cb) {
        us8 o;
#pragma unroll
        for (int q = 0; q < 8; ++q) o[q] = f2b(s[q]);
        *(us8*)(J.Cb + (size_t)i8 * 8) = o;
    }
}

// =====================================================================
// relj finalize + fused scores. Grid 512 x 256: block = 2 edges.
// relj = sum_z bf16planes + gather(a_s/a_o partials, 2 planes each)
// s_sbj[e] = <relj[e], sum_z qW_s partials[i_e]>/32 ; s_obj likewise (j_e)
// =====================================================================
__global__ __launch_bounds__(256)
void k_relj_sc(const unsigned short* __restrict__ P, int KS,
               const float* __restrict__ gA,     // a_s planes; a_o at +131072; z-stride 65536
               const float* __restrict__ qsP,    // qW_s planes (2, z-stride 65536)
               const float* __restrict__ qoP,    // qW_o planes
               const int* __restrict__ eidx,
               float* __restrict__ Cf, unsigned short* __restrict__ Cb,
               float* __restrict__ s_sbj, float* __restrict__ s_obj)
{
    __shared__ float wred[8];
    const int t = threadIdx.x;
    const int i8 = blockIdx.x * 256 + t;
    float s[8] = {0.f, 0.f, 0.f, 0.f, 0.f, 0.f, 0.f, 0.f};
    for (int z = 0; z < KS; ++z) {
        const us8 v = *(const us8*)(P + (size_t)z * 1048576 + (size_t)i8 * 8);
#pragma unroll
        for (int q = 0; q < 8; ++q) s[q] += b2f(v[q]);
    }
    const int e = i8 >> 7, c8 = i8 & 127;
    const int idx = eidx[e];
    const int in_ = idx >> 6, jn = idx & 63;
    const float* as_ = gA + (size_t)in_ * 1024 + c8 * 8;
    const float* ao_ = gA + 131072 + (size_t)jn * 1024 + c8 * 8;
    for (int z = 0; z < 2; ++z) {
#pragma unroll
        for (int q = 0; q < 8; ++q)
            s[q] += as_[(size_t)z * 65536 + q] + ao_[(size_t)z * 65536 + q];
    }
    // write relj (f32 + bf16)
    *(float4*)(Cf + (size_t)i8 * 8)     = make_float4(s[0], s[1], s[2], s[3]);
    *(float4*)(Cf + (size_t)i8 * 8 + 4) = make_float4(s[4], s[5], s[6], s[7]);
    us8 o;
#pragma unroll
    for (int q = 0; q < 8; ++q) o[q] = f2b(s[q]);
    *(us8*)(Cb + (size_t)i8 * 8) = o;
    // fused scores: gather qW partials, dot, block-reduce
    float qs[8] = {0.f, 0.f, 0.f, 0.f, 0.f, 0.f, 0.f, 0.f};
    float qo[8] = {0.f, 0.f, 0.f, 0.f, 0.f, 0.f, 0.f, 0.f};
    const float* qsp = qsP + (size_t)in_ * 1024 + c8 * 8;
    const float* qop = qoP + (size_t)jn * 1024 + c8 * 8;
    for (int z = 0; z < 2; ++z) {
#pragma unroll
        for (int q = 0; q < 8; ++q) {
            qs[q] += qsp[(size_t)z * 65536 + q];
            qo[q] += qop[(size_t)z * 65536 + q];
        }
    }
    float vs = 0.f, vo = 0.f;
#pragma unroll
    for (int q = 0; q < 8; ++q) { vs += s[q] * qs[q]; vo += s[q] * qo[q]; }
    for (int off = 32; off; off >>= 1) {
        vs += __shfl_down(vs, off);
        vo += __shfl_down(vo, off);
    }
    const int wid = t >> 6;
    if ((t & 63) == 0) { wred[wid] = vs; wred[4 + wid] = vo; }
    __syncthreads();
    if (t == 0) {
        s_sbj[e] = (wred[0] + wred[1]) * 0.03125f;
        s_obj[e] = (wred[4] + wred[5]) * 0.03125f;
    } else if (t == 128) {
        s_sbj[e] = (wred[2] + wred[3]) * 0.03125f;
        s_obj[e] = (wred[6] + wred[7]) * 0.03125f;
    }
}

// batched f32 -> bf16 conversion (7 matrices), one launch
struct ConvBatch { const float* s[7]; unsigned short* d[7]; int beg8[7]; int total8; };
__global__ void k_f2b_batch(ConvBatch cb)
{
    int i = blockIdx.x * blockDim.x + threadIdx.x;
    if (i >= cb.total8) return;
    int k = 0;
    while (k < 6 && i >= cb.beg8[k + 1]) ++k;
    const int j = i - cb.beg8[k];
    const float4 v0 = reinterpret_cast<const float4*>(cb.s[k])[2 * j];
    const float4 v1 = reinterpret_cast<const float4*>(cb.s[k])[2 * j + 1];
    const bf16x8 o = cvt8(v0, v1);
    *(bf16x8*)(cb.d[k] + (size_t)j * 8) = o;
}

// transpose 4 f32 [1024][1024] matrices into bf16 (dst[k][o] = src[o][k])
struct T4 { const float* s[4]; unsigned short* d[4]; };
__global__ __launch_bounds__(256)
void k_transpose(T4 t4)
{
    __shared__ float tile[64][65];
    const float* __restrict__ src = t4.s[blockIdx.z];
    unsigned short* __restrict__ dst = t4.d[blockIdx.z];
    const int bx = blockIdx.x * 64, by = blockIdx.y * 64;
    const int c = threadIdx.x & 63, r0 = threadIdx.x >> 6;
#pragma unroll
    for (int h = 0; h < 16; ++h) {
        const int r = r0 * 16 + h;
        tile[r][c] = src[(size_t)(by + r) * 1024 + bx + c];
    }
    __syncthreads();
#pragma unroll
    for (int h = 0; h < 16; ++h) {
        const int kk = r0 * 16 + h;
        dst[(size_t)(bx + kk) * 1024 + by + c] = f2b(tile[c][kk]);
    }
}

// build folded joint weights from W (1024 x 4096, slices W1|W2|W3|W4):
// z=0 (rel, s=+1):  rt = W1+W4,  eff = [W2-W4 | W3]
// z=1 (vj,  s=-1):  rt = W1-W4,  eff = [W2+W4 | W3]
__global__ __launch_bounds__(256)
void k_buildW(const float* __restrict__ Wrel, const float* __restrict__ Wjnt,
              unsigned short* __restrict__ WrtRel, unsigned short* __restrict__ WeffRel,
              unsigned short* __restrict__ UrtVj, unsigned short* __restrict__ UeffVj)
{
    const int idx = blockIdx.x * 256 + threadIdx.x;     // [0, 1024*256)
    const int o = idx >> 8, j = (idx & 255) * 4;
    const float* W = blockIdx.z ? Wjnt : Wrel;
    const float sgn = blockIdx.z ? -1.f : 1.f;
    unsigned short* rt = blockIdx.z ? UrtVj : WrtRel;
    unsigned short* ef = blockIdx.z ? UeffVj : WeffRel;
    const float4 w1 = *(const float4*)(W + (size_t)o * 4096 + j);
    const float4 w2 = *(const float4*)(W + (size_t)o * 4096 + 1024 + j);
    const float4 w3 = *(const float4*)(W + (size_t)o * 4096 + 2048 + j);
    const float4 w4 = *(const float4*)(W + (size_t)o * 4096 + 3072 + j);
    us4 t;
    t.x = f2b(w1.x + sgn * w4.x); t.y = f2b(w1.y + sgn * w4.y);
    t.z = f2b(w1.z + sgn * w4.z); t.w = f2b(w1.w + sgn * w4.w);
    *(us4*)(rt + (size_t)o * 1024 + j) = t;
    t.x = f2b(w2.x - sgn * w4.x); t.y = f2b(w2.y - sgn * w4.y);
    t.z = f2b(w2.z - sgn * w4.z); t.w = f2b(w2.w - sgn * w4.w);
    *(us4*)(ef + (size_t)o * 2048 + j) = t;
    t.x = f2b(w3.x); t.y = f2b(w3.y); t.z = f2b(w3.z); t.w = f2b(w3.w);
    *(us4*)(ef + (size_t)o * 2048 + 1024 + j) = t;
}

// fused softmax + weighted aggregation -> bf16 ctx outputs
__global__ __launch_bounds__(256)
void k_ctx12(const float* __restrict__ relj, const float* __restrict__ s_sbj,
             const float* __restrict__ s_obj, const int* __restrict__ conn,
             unsigned short* __restrict__ ctx1b, unsigned short* __restrict__ ctx2b)
{
    const int bid = blockIdx.x, t = threadIdx.x;
    const float4* relj4 = reinterpret_cast<const float4*>(relj);
    float4 acc = make_float4(0.f, 0.f, 0.f, 0.f);
    if (bid < 64) {
        const int i = bid;
        float sv[16];
        float m = -1e30f;
#pragma unroll
        for (int q = 0; q < 16; ++q) { sv[q] = s_sbj[i * 16 + q]; m = fmaxf(m, sv[q]); }
        float sum = 0.f;
#pragma unroll
        for (int q = 0; q < 16; ++q) { sv[q] = expf(sv[q] - m); sum += sv[q]; }
        const float inv = 1.f / sum;
#pragma unroll
        for (int q = 0; q < 16; ++q) {
            const float w = sv[q] * inv;
            const float4 v = relj4[(size_t)(i * 16 + q) * 256 + t];
            acc.x += w * v.x; acc.y += w * v.y; acc.z += w * v.z; acc.w += w * v.w;
        }
        us4 o; o.x = f2b(acc.x); o.y = f2b(acc.y); o.z = f2b(acc.z); o.w = f2b(acc.w);
        *(us4*)(ctx1b + (size_t)bid * 1024 + t * 4) = o;
    } else {
        const int j = bid - 64;
        __shared__ float sl[64];
        __shared__ int el[64];
        if (t < 64) {
            const int e = conn[t * kN + j];
            el[t] = e;
            sl[t] = (e >= 0) ? s_obj[e] : -1e30f;
        }
        __syncthreads();
        float m = -1e30f;
        for (int i = 0; i < 64; ++i) m = fmaxf(m, sl[i]);
        __syncthreads();
        if (t < 64) sl[t] = (el[t] >= 0) ? expf(sl[t] - m) : 0.f;
        __syncthreads();
        float sum = 0.f;
        for (int i = 0; i < 64; ++i) sum += sl[i];
        const float inv = 1.f / sum;
        for (int i = 0; i < 64; ++i) {
            const int e = el[i];
            if (e >= 0) {
                const float w = sl[i] * inv;
                const float4 v = relj4[(size_t)e * 256 + t];
                acc.x += w * v.x; acc.y += w * v.y; acc.z += w * v.z; acc.w += w * v.w;
            }
        }
        us4 o; o.x = f2b(acc.x); o.y = f2b(acc.y); o.z = f2b(acc.z); o.w = f2b(acc.w);
        *(us4*)(ctx2b + (size_t)j * 1024 + t * 4) = o;
    }
}

// =====================================================================
extern "C" void kernel_launch(void* const* d_in, const int* in_sizes, int n_in,
                              void* d_out, int out_size, void* d_ws, size_t ws_size,
                              hipStream_t stream)
{
    const float* visual   = (const float*)d_in[0];
    const float* relvis   = (const float*)d_in[1];
    const int*   conn     = (const int*)d_in[2];
    const int*   edge_idx = (const int*)d_in[4];
    const float* W_sub    = (const float*)d_in[5];
    const float* W_obj    = (const float*)d_in[6];
    const float* W_r2s    = (const float*)d_in[7];
    const float* W_r2o    = (const float*)d_in[8];
    const float* W_joint  = (const float*)d_in[9];
    const float* W_ctx    = (const float*)d_in[10];
    const float* W_relu   = (const float*)d_in[11];  // (D,3D): Ws|Wo|Wr
    const float* W_relj   = (const float*)d_in[12];
    const float* W_relc   = (const float*)d_in[13];
    const float* W_node   = (const float*)d_in[14];
    const float* b_node   = (const float*)d_in[15];
    const float* W_factor = (const float*)d_in[16];
    (void)in_sizes; (void)n_in; (void)out_size; (void)ws_size;

    float* ws = (float*)d_ws;
    size_t off = 0;
    auto allocF = [&](size_t n) { float* p = ws + off; off += n; return p; };
    auto allocU = [&](size_t n) { return (unsigned short*)allocF((n + 1) / 2); };

    float* partF = allocF((size_t)1024 * 1024);                // f32 partials (skinny)
    unsigned short* partB = allocU((size_t)16 * 1024 * 1024);  // bf16 partials
    float* G0p  = allocF((size_t)4 * 65536);                   // G0 f32 planes (persist)
    unsigned short* R0p = allocU((size_t)4 * 1024 * 1024);     // R0 bf16 planes (persist)
    float* relj  = allocF((size_t)kE * kD);
    float* s_sbj = allocF(kE);
    float* s_obj = allocF(kE);
    unsigned short* relvis_b = allocU((size_t)kE * kD);
    unsigned short* visual_b = allocU((size_t)kN * kD);
    unsigned short* vj_b   = allocU((size_t)kN * kD);
    unsigned short* rj_b   = allocU((size_t)kE * kD);
    unsigned short* relj_b = allocU((size_t)kE * kD);
    unsigned short* rc_bA  = allocU((size_t)kE * kD);
    unsigned short* rc_bB  = allocU((size_t)kE * kD);
    unsigned short* vctx_bA = allocU((size_t)kN * kD);
    unsigned short* vctx_bB = allocU((size_t)kN * kD);
    unsigned short* ctx1_b = allocU((size_t)kN * kD);
    unsigned short* ctx2_b = allocU((size_t)kN * kD);
    unsigned short* Wb_ctx    = allocU((size_t)kD * 3 * kD);
    unsigned short* Wb_relu   = allocU((size_t)kD * 3 * kD);
    unsigned short* Wb_relc   = allocU((size_t)kD * 2 * kD);
    unsigned short* Wb_node   = allocU((size_t)kD * 2 * kD);
    unsigned short* Wb_factor = allocU((size_t)kD * 2 * kD);
    unsigned short* WsubT = allocU((size_t)kD * kD);
    unsigned short* WobjT = allocU((size_t)kD * kD);
    unsigned short* Wr2sT = allocU((size_t)kD * kD);
    unsigned short* Wr2oT = allocU((size_t)kD * kD);
    unsigned short* Wc_s  = allocU((size_t)kD * kD);
    unsigned short* Wc_o  = allocU((size_t)kD * kD);
    unsigned short* WrtRel  = allocU((size_t)kD * kD);      // W1+W4
    unsigned short* WeffRel = allocU((size_t)kD * 2 * kD);  // [W2-W4 | W3]
    unsigned short* UrtVj   = allocU((size_t)kD * kD);      // U1-U4
    unsigned short* UeffVj  = allocU((size_t)kD * 2 * kD);  // [U2+U4 | U3]

    auto seg1 = [](const unsigned short* a) {
        ASrc s; s.s0 = a; s.s1 = nullptr; s.s2 = nullptr; s.mode = 1; return s;
    };
    auto seg2 = [](const unsigned short* a, const unsigned short* b) {
        ASrc s; s.s0 = a; s.s1 = b; s.s2 = nullptr; s.mode = 1; return s;
    };
    auto seg3 = [](const unsigned short* a, const unsigned short* b, const unsigned short* c) {
        ASrc s; s.s0 = a; s.s1 = b; s.s2 = c; s.mode = 1; return s;
    };
    auto prodA = [](const unsigned short* c, const unsigned short* x) {  // [c | c*x]
        ASrc s; s.s0 = c; s.s1 = x; s.s2 = nullptr; s.mode = 2; return s;
    };

    // ---- job-list launch helpers ----
    GJobs G; RJobs R;
    int gn = 0, gt = 0, rn = 0, rtt = 0;
    auto gAdd = [&](ASrc a, const unsigned short* W, int ldw, void* P, int M, int K, int KS, int pbf) {
        G.j[gn].a = a; G.j[gn].W = W; G.j[gn].ldw = ldw; G.j[gn].P = P;
        G.j[gn].M = M; G.j[gn].K = K; G.j[gn].KS = KS; G.j[gn].pbf = pbf;
        G.t0[gn] = gt; gt += KS * (M >> 6) * 8; ++gn;
    };
    auto gLaunch = [&]() {
        G.nj = gn; G.t0[gn] = gt;
        hipLaunchKernelGGL(k_gemm, dim3(gt), dim3(256), 0, stream, G);
        gn = 0; gt = 0;
    };
    auto rAdd = [&](const void* P, int MO8, int KS, int pbf,
                    const void* P2, int KS2, int pbf2,
                    float* Cf, unsigned short* Cb,
                    const unsigned short* addb, const float* bias) {
        R.j[rn].P = P; R.j[rn].MO8 = MO8; R.j[rn].KS = KS; R.j[rn].pbf = pbf;
        R.j[rn].P2 = P2; R.j[rn].KS2 = KS2; R.j[rn].pbf2 = pbf2;
        R.j[rn].Cf = Cf; R.j[rn].Cb = Cb; R.j[rn].addb = addb; R.j[rn].bias = bias;
        R.t0[rn] = rtt; rtt += (MO8 + 255) / 256; ++rn;
    };
    auto rLaunch = [&]() {
        R.nj = rn; R.t0[rn] = rtt;
        hipLaunchKernelGGL(k_reduce, dim3(rtt), dim3(256), 0, stream, R);
        rn = 0; rtt = 0;
    };

    // ---- setup (3 launches; setup GEMMs folded into iter-0 L1/L2) ----
    {
        ConvBatch cb;
        const float* srcs[7] = {W_ctx, W_relu, W_relc, W_node, W_factor, relvis, visual};
        unsigned short* dsts[7] = {Wb_ctx, Wb_relu, Wb_relc, Wb_node, Wb_factor, relvis_b, visual_b};
        const int nel[7] = {3 * 1024 * 1024, 3 * 1024 * 1024, 2 * 1024 * 1024,
                            2 * 1024 * 1024, 2 * 1024 * 1024, 1024 * 1024, 64 * 1024};
        int cum = 0;
        for (int k = 0; k < 7; ++k) { cb.s[k] = srcs[k]; cb.d[k] = dsts[k]; cb.beg8[k] = cum; cum += nel[k] / 8; }
        cb.total8 = cum;
        hipLaunchKernelGGL(k_f2b_batch, dim3((cum + 255) / 256), dim3(256), 0, stream, cb);
    }
    {
        T4 t4;
        t4.s[0] = W_sub; t4.d[0] = WsubT;
        t4.s[1] = W_obj; t4.d[1] = WobjT;
        t4.s[2] = W_r2s; t4.d[2] = Wr2sT;
        t4.s[3] = W_r2o; t4.d[3] = Wr2oT;
        hipLaunchKernelGGL(k_transpose, dim3(16, 16, 4), dim3(256), 0, stream, t4);
    }
    hipLaunchKernelGGL(k_buildW, dim3(1024, 1, 2), dim3(256), 0, stream,
                       W_relj, W_joint, WrtRel, WeffRel, UrtVj, UeffVj);

    const size_t M8 = (size_t)8 * 1024 * 1024;    // bf16 elems
    const size_t M12 = (size_t)12 * 1024 * 1024;

    // ---- T iterations ----
    for (int t = 0; t < kT; ++t) {
        const unsigned short* vcur  = (t == 0) ? visual_b : vctx_bA;
        unsigned short*       vnext = (t == 0) ? vctx_bA : vctx_bB;
        const unsigned short* rccur = (t == 0) ? relvis_b : rc_bA;
        unsigned short*       rcnext = (t == 0) ? rc_bA : rc_bB;

        // L1: vj (f32 KS=8) + rj (bf16 KS=8); iter0 adds Wc_s, Wc_o, R0, G0
        gAdd(prodA(vcur, visual_b), UeffVj, 2048, partF, 64, 2048, 8, 0);
        gAdd(prodA(rccur, relvis_b), WeffRel, 2048, partB, 1024, 2048, 8, 1);
        if (t == 0) {
            gAdd(seg1(Wr2sT), WsubT, 1024, partB + M8,  1024, 1024, 4, 1);   // Wc_s planes
            gAdd(seg1(Wr2oT), WobjT, 1024, partB + M12, 1024, 1024, 4, 1);   // Wc_o planes
            gAdd(seg1(relvis_b), WrtRel, 1024, R0p, 1024, 1024, 4, 1);       // R0 planes
            gAdd(seg1(visual_b), UrtVj, 1024, G0p, 64, 1024, 4, 0);          // G0 planes
        }
        gLaunch();
        // L2: vj = sum(vj planes) + sum(G0 planes) -> bf16
        //     rj = sum(rj planes) + sum(R0 planes) -> bf16 ; iter0: finalize Wc_s/Wc_o
        rAdd(partF, 8192, 8, 0, G0p, 4, 0, nullptr, vj_b, nullptr, nullptr);
        rAdd(partB, 131072, 8, 1, R0p, 4, 1, nullptr, rj_b, nullptr, nullptr);
        if (t == 0) {
            rAdd(partB + M8,  131072, 4, 1, nullptr, 0, 0, nullptr, Wc_s, nullptr, nullptr);
            rAdd(partB + M12, 131072, 4, 1, nullptr, 0, 0, nullptr, Wc_o, nullptr, nullptr);
        }
        rLaunch();

        // L3: asqw partials (4 skinny, f32 KS=2) + relj (bf16 KS=4)
        gAdd(seg1(vj_b), Wb_relu,        3072, partF,          64, 1024, 2, 0);  // a_s planes
        gAdd(seg1(vj_b), Wb_relu + 1024, 3072, partF + 131072, 64, 1024, 2, 0);  // a_o planes
        gAdd(seg1(vj_b), Wc_s,           1024, partF + 262144, 64, 1024, 2, 0);  // qW_s planes
        gAdd(seg1(vj_b), Wc_o,           1024, partF + 393216, 64, 1024, 2, 0);  // qW_o planes
        gAdd(seg1(rj_b), Wb_relu + 2048, 3072, partB,        1024, 1024, 4, 1);  // relj planes
        gLaunch();

        // L4: relj finalize + fused scores (one 512-block kernel)
        hipLaunchKernelGGL(k_relj_sc, dim3(512), dim3(256), 0, stream,
                           partB, 4, partF, partF + 262144, partF + 393216,
                           edge_idx, relj, relj_b, s_sbj, s_obj);

        // softmax + aggregation (bf16 ctx out)
        hipLaunchKernelGGL(k_ctx12, dim3(128), dim3(256), 0, stream,
                           relj, s_sbj, s_obj, conn, ctx1_b, ctx2_b);

        // L7: vctx' + rc'
        gAdd(seg3(vcur, ctx1_b, ctx2_b), Wb_ctx, 3072, partF, 64, 3072, 8, 0);
        gAdd(seg2(rccur, relj_b), Wb_relc, 2048, partB, 1024, 2048, 8, 1);
        gLaunch();
        // L8
        rAdd(partF, 8192, 8, 0, nullptr, 0, 0, nullptr, vnext, nullptr, nullptr);
        rAdd(partB, 131072, 8, 1, nullptr, 0, 0, nullptr, rcnext, nullptr, nullptr);
        rLaunch();
    }

    float* rel_out = (float*)d_out;
    float* v_out   = (float*)d_out + (size_t)kE * kD;
    // F1: rel_out (bf16 partials KS=4) + v_out (f32 partials KS=8, skinny)
    gAdd(seg2(relvis_b, rc_bB), Wb_factor, 2048, partB, 1024, 2048, 4, 1);
    gAdd(seg2(visual_b, vctx_bB), Wb_node, 2048, partF, 64, 2048, 8, 0);
    gLaunch();
    // F2
    rAdd(partB, 131072, 4, 1, nullptr, 0, 0, rel_out, nullptr, nullptr, nullptr);
    rAdd(partF, 8192, 8, 0, nullptr, 0, 0, v_out, nullptr, nullptr, b_node);
    rLaunch();
}

// Round 15
// 206.193 us; speedup vs baseline: 2.9403x; 1.0107x over previous
//
#include <hip/hip_runtime.h>

// ---- problem constants ----
static constexpr int kN = 64;    // nodes
static constexpr int kD = 1024;  // feature dim
static constexpr int kE = 1024;  // edges (16 per row, row-major by (i,j))
static constexpr int kT = 2;     // iterations

typedef short  bf16x8 __attribute__((ext_vector_type(8)));
typedef float  f32x4  __attribute__((ext_vector_type(4)));
typedef unsigned short us8 __attribute__((ext_vector_type(8)));
typedef unsigned short us4 __attribute__((ext_vector_type(4)));

__device__ __forceinline__ unsigned short f2b(float f) {
    unsigned int u = __builtin_bit_cast(unsigned int, f);
    u += 0x7FFFu + ((u >> 16) & 1u);          // RNE
    return (unsigned short)(u >> 16);
}
__device__ __forceinline__ float b2f(unsigned short u) {
    unsigned int x = ((unsigned int)u) << 16;
    return __builtin_bit_cast(float, x);
}
__device__ __forceinline__ bf16x8 cvt8(float4 a, float4 b) {
    us8 o;
    o[0] = f2b(a.x); o[1] = f2b(a.y); o[2] = f2b(a.z); o[3] = f2b(a.w);
    o[4] = f2b(b.x); o[5] = f2b(b.y); o[6] = f2b(b.z); o[7] = f2b(b.w);
    return __builtin_bit_cast(bf16x8, o);
}

// A-operand source, ALL bf16 [row][1024] segments:
// mode 1: concat of segments s0|s1|s2 ; mode 2: [s0 | s0*s1]
struct ASrc { const unsigned short* s0; const unsigned short* s1; const unsigned short* s2; int mode; };

__device__ __forceinline__ bf16x8 loadA8(const ASrc& s, int row, int kg) {
    const int seg = kg >> 10, k = kg & 1023;
    const size_t ro = (size_t)row * 1024 + k;
    if (s.mode == 1) {
        const unsigned short* p = (seg == 0) ? s.s0 : (seg == 1 ? s.s1 : s.s2);
        return *(const bf16x8*)(p + ro);
    }
    const bf16x8 a = *(const bf16x8*)(s.s0 + ro);
    if (seg == 0) return a;
    const bf16x8 b = *(const bf16x8*)(s.s1 + ro);
    const us8 ua = __builtin_bit_cast(us8, a), ub = __builtin_bit_cast(us8, b);
    us8 o;
#pragma unroll
    for (int q = 0; q < 8; ++q) o[q] = f2b(b2f(ua[q]) * b2f(ub[q]));
    return __builtin_bit_cast(bf16x8, o);
}

// =====================================================================
// Job-list MFMA GEMM: uniform 64-row x 128-col tile, 4 waves (2x2), BK=64.
// A+B staged via swizzled LDS. pbf: bf16 partials via LDS-coalesced
// epilogue; else f32 direct. Row-tile fastest -> XCD-affine A reuse.
// NO device-scope fences (R12 lesson: __threadfence costs ~100us at scale).
// =====================================================================
struct GJob { ASrc a; const unsigned short* W; int ldw; void* P; int M; int K; int KS; int pbf; };
struct GJobs { GJob j[6]; int t0[7]; int nj; };

__global__ __launch_bounds__(256)
void k_gemm(GJobs G)
{
    __shared__ unsigned short lds[12288];   // As[64][64] | Bs[128][64]; epi Cs[64][132]
    const int flat = blockIdx.x;
    int ji = 0;
    while (ji + 1 < G.nj && flat >= G.t0[ji + 1]) ++ji;
    const GJob J = G.j[ji];
    const int local = flat - G.t0[ji];
    const int rowTiles = J.M >> 6;
    const int rt = local & (rowTiles - 1);          // fastest -> XCD affinity
    const int rest = local / rowTiles;
    const int ct = rest & 7, z = rest >> 3;
    const int rowBase = rt * 64, colBase = ct * 128;
    const int kchunk = J.K / J.KS, kbeg = z * kchunk, kend = kbeg + kchunk;

    const int tid = threadIdx.x, lane = tid & 63, wid = tid >> 6;
    const int l15 = lane & 15, l4 = lane >> 4;
    const int sr = tid >> 3, sc8 = tid & 7;
    const int wc8 = (sc8 ^ (sr & 7)) * 8;
    const int wr = wid >> 1, wc = wid & 1;

    bf16x8 ra[2], rb[4];
    auto stage = [&](int kt) {
#pragma unroll
        for (int h = 0; h < 2; ++h)
            ra[h] = loadA8(J.a, rowBase + sr + 32 * h, kt + sc8 * 8);
#pragma unroll
        for (int h = 0; h < 4; ++h)
            rb[h] = *(const bf16x8*)(J.W + (size_t)(colBase + sr + 32 * h) * J.ldw + kt + sc8 * 8);
    };

    f32x4 acc[2][4] = {};
    stage(kbeg);
    for (int kt = kbeg; kt < kend; kt += 64) {
        __syncthreads();
#pragma unroll
        for (int h = 0; h < 2; ++h)
            *(bf16x8*)&lds[(sr + 32 * h) * 64 + wc8] = ra[h];
#pragma unroll
        for (int h = 0; h < 4; ++h)
            *(bf16x8*)&lds[4096 + (sr + 32 * h) * 64 + wc8] = rb[h];
        __syncthreads();
        if (kt + 64 < kend) stage(kt + 64);
#pragma unroll
        for (int kk = 0; kk < 2; ++kk) {
            const int c8 = kk * 4 + l4;
            bf16x8 af[2], bv[4];
#pragma unroll
            for (int m = 0; m < 2; ++m) {
                const int ar = wr * 32 + m * 16 + l15;
                af[m] = *(const bf16x8*)&lds[ar * 64 + (c8 ^ (ar & 7)) * 8];
            }
#pragma unroll
            for (int n = 0; n < 4; ++n) {
                const int br = wc * 64 + n * 16 + l15;
                bv[n] = *(const bf16x8*)&lds[4096 + br * 64 + (c8 ^ (br & 7)) * 8];
            }
#pragma unroll
            for (int m = 0; m < 2; ++m)
#pragma unroll
                for (int n = 0; n < 4; ++n)
                    acc[m][n] = __builtin_amdgcn_mfma_f32_16x16x32_bf16(af[m], bv[n], acc[m][n], 0, 0, 0);
        }
    }

    if (J.pbf) {
        __syncthreads();
#pragma unroll
        for (int m = 0; m < 2; ++m)
#pragma unroll
            for (int n = 0; n < 4; ++n)
#pragma unroll
                for (int r = 0; r < 4; ++r)
                    lds[(wr * 32 + m * 16 + l4 * 4 + r) * 132 + wc * 64 + n * 16 + l15] =
                        f2b(acc[m][n][r]);
        __syncthreads();
        unsigned short* Pb = (unsigned short*)J.P + (size_t)z * J.M * 1024;
#pragma unroll
        for (int c = tid; c < 1024; c += 256) {
            const int row = c >> 4, ch = c & 15;
            *(bf16x8*)(Pb + (size_t)(rowBase + row) * 1024 + colBase + ch * 8) =
                *(const bf16x8*)&lds[row * 132 + ch * 8];
        }
    } else {
        float* base = (float*)J.P + (size_t)z * J.M * 1024;
#pragma unroll
        for (int m = 0; m < 2; ++m) {
            const int row = rowBase + wr * 32 + m * 16 + l4 * 4;
#pragma unroll
            for (int n = 0; n < 4; ++n) {
                const int col = colBase + wc * 64 + n * 16 + l15;
#pragma unroll
                for (int r = 0; r < 4; ++r)
                    base[(size_t)(row + r) * 1024 + col] = acc[m][n][r];
            }
        }
    }
}

// =====================================================================
// Job-list split-K reduce, 8-elem granularity.
// out = sum planes of P (KS, pbf) [+ planes of P2 (KS2, pbf2)]
//       (+addb bf16) (+bias)
// =====================================================================
struct RJob { const void* P; int MO8; int KS; int pbf;
              const void* P2; int KS2; int pbf2;
              float* Cf; unsigned short* Cb;
              const unsigned short* addb; const float* bias; };
struct RJobs { RJob j[6]; int t0[7]; int nj; };

__global__ void k_reduce(RJobs R)
{
    const int flat = blockIdx.x;
    int ji = 0;
    while (ji + 1 < R.nj && flat >= R.t0[ji + 1]) ++ji;
    const RJob J = R.j[ji];
    const int i8 = (flat - R.t0[ji]) * 256 + threadIdx.x;
    if (i8 >= J.MO8) return;
    float s[8] = {0.f, 0.f, 0.f, 0.f, 0.f, 0.f, 0.f, 0.f};
    if (J.pbf) {
        const unsigned short* P = (const unsigned short*)J.P;
        for (int z = 0; z < J.KS; ++z) {
            const us8 v = *(const us8*)(P + (size_t)z * J.MO8 * 8 + (size_t)i8 * 8);
#pragma unroll
            for (int q = 0; q < 8; ++q) s[q] += b2f(v[q]);
        }
    } else {
        const float* P = (const float*)J.P;
        for (int z = 0; z < J.KS; ++z) {
            const float* p = P + (size_t)z * J.MO8 * 8 + (size_t)i8 * 8;
            const float4 v0 = *(const float4*)p;
            const float4 v1 = *(const float4*)(p + 4);
            s[0] += v0.x; s[1] += v0.y; s[2] += v0.z; s[3] += v0.w;
            s[4] += v1.x; s[5] += v1.y; s[6] += v1.z; s[7] += v1.w;
        }
    }
    if (J.P2) {
        if (J.pbf2) {
            const unsigned short* P = (const unsigned short*)J.P2;
            for (int z = 0; z < J.KS2; ++z) {
                const us8 v = *(const us8*)(P + (size_t)z * J.MO8 * 8 + (size_t)i8 * 8);
#pragma unroll
                for (int q = 0; q < 8; ++q) s[q] += b2f(v[q]);
            }
        } else {
            const float* P = (const float*)J.P2;
            for (int z = 0; z < J.KS2; ++z) {
                const float* p = P + (size_t)z * J.MO8 * 8 + (size_t)i8 * 8;
                const float4 v0 = *(const float4*)p;
                const float4 v1 = *(const float4*)(p + 4);
                s[0] += v0.x; s[1] += v0.y; s[2] += v0.z; s[3] += v0.w;
                s[4] += v1.x; s[5] += v1.y; s[6] += v1.z; s[7] += v1.w;
            }
        }
    }
    if (J.addb) {
        const us8 v = *(const us8*)(J.addb + (size_t)i8 * 8);
#pragma unroll
        for (int q = 0; q < 8; ++q) s[q] += b2f(v[q]);
    }
    if (J.bias) {
        const int c8 = i8 & 127;
#pragma unroll
        for (int q = 0; q < 8; ++q) s[q] += J.bias[c8 * 8 + q];
    }
    if (J.Cf) {
        *(float4*)(J.Cf + (size_t)i8 * 8)     = make_float4(s[0], s[1], s[2], s[3]);
        *(float4*)(J.Cf + (size_t)i8 * 8 + 4) = make_float4(s[4], s[5], s[6], s[7]);
    }
    if (J.Cb) {
        us8 o;
#pragma unroll
        for (int q = 0; q < 8; ++q) o[q] = f2b(s[q]);
        *(us8*)(J.Cb + (size_t)i8 * 8) = o;
    }
}

// =====================================================================
// relj finalize + fused scores. Grid 512 x 256: block = 2 edges.
// =====================================================================
__global__ __launch_bounds__(256)
void k_relj_sc(const unsigned short* __restrict__ P, int KS,
               const float* __restrict__ gA,     // a_s planes; a_o at +131072; z-stride 65536
               const float* __restrict__ qsP,    // qW_s planes (2, z-stride 65536)
               const float* __restrict__ qoP,    // qW_o planes
               const int* __restrict__ eidx,
               float* __restrict__ Cf, unsigned short* __restrict__ Cb,
               float* __restrict__ s_sbj, float* __restrict__ s_obj)
{
    __shared__ float wred[8];
    const int t = threadIdx.x;
    const int i8 = blockIdx.x * 256 + t;
    float s[8] = {0.f, 0.f, 0.f, 0.f, 0.f, 0.f, 0.f, 0.f};
    for (int z = 0; z < KS; ++z) {
        const us8 v = *(const us8*)(P + (size_t)z * 1048576 + (size_t)i8 * 8);
#pragma unroll
        for (int q = 0; q < 8; ++q) s[q] += b2f(v[q]);
    }
    const int e = i8 >> 7, c8 = i8 & 127;
    const int idx = eidx[e];
    const int in_ = idx >> 6, jn = idx & 63;
    const float* as_ = gA + (size_t)in_ * 1024 + c8 * 8;
    const float* ao_ = gA + 131072 + (size_t)jn * 1024 + c8 * 8;
    for (int z = 0; z < 2; ++z) {
#pragma unroll
        for (int q = 0; q < 8; ++q)
            s[q] += as_[(size_t)z * 65536 + q] + ao_[(size_t)z * 65536 + q];
    }
    *(float4*)(Cf + (size_t)i8 * 8)     = make_float4(s[0], s[1], s[2], s[3]);
    *(float4*)(Cf + (size_t)i8 * 8 + 4) = make_float4(s[4], s[5], s[6], s[7]);
    us8 o;
#pragma unroll
    for (int q = 0; q < 8; ++q) o[q] = f2b(s[q]);
    *(us8*)(Cb + (size_t)i8 * 8) = o;
    float qs[8] = {0.f, 0.f, 0.f, 0.f, 0.f, 0.f, 0.f, 0.f};
    float qo[8] = {0.f, 0.f, 0.f, 0.f, 0.f, 0.f, 0.f, 0.f};
    const float* qsp = qsP + (size_t)in_ * 1024 + c8 * 8;
    const float* qop = qoP + (size_t)jn * 1024 + c8 * 8;
    for (int z = 0; z < 2; ++z) {
#pragma unroll
        for (int q = 0; q < 8; ++q) {
            qs[q] += qsp[(size_t)z * 65536 + q];
            qo[q] += qop[(size_t)z * 65536 + q];
        }
    }
    float vs = 0.f, vo = 0.f;
#pragma unroll
    for (int q = 0; q < 8; ++q) { vs += s[q] * qs[q]; vo += s[q] * qo[q]; }
    for (int off = 32; off; off >>= 1) {
        vs += __shfl_down(vs, off);
        vo += __shfl_down(vo, off);
    }
    const int wid = t >> 6;
    if ((t & 63) == 0) { wred[wid] = vs; wred[4 + wid] = vo; }
    __syncthreads();
    if (t == 0) {
        s_sbj[e] = (wred[0] + wred[1]) * 0.03125f;
        s_obj[e] = (wred[4] + wred[5]) * 0.03125f;
    } else if (t == 128) {
        s_sbj[e] = (wred[2] + wred[3]) * 0.03125f;
        s_obj[e] = (wred[6] + wred[7]) * 0.03125f;
    }
}

// =====================================================================
// merged setup: f2b batch conv | 4x transpose | buildW  (one launch)
// block ranges: [0, nf2b) f2b ; [nf2b, nf2b+1024) transpose ; rest buildW
// =====================================================================
struct ConvBatch { const float* s[7]; unsigned short* d[7]; int beg8[7]; int total8; };
struct SetupArgs {
    ConvBatch cb; int nf2b;
    const float* ts[4]; unsigned short* td[4];
    const float* Wrel; const float* Wjnt;
    unsigned short *WrtRel, *WeffRel, *UrtVj, *UeffVj;
};

__global__ __launch_bounds__(256)
void k_setup(SetupArgs S)
{
    __shared__ float tile[64][65];
    const int b = blockIdx.x, t = threadIdx.x;
    if (b < S.nf2b) {
        const int i = b * 256 + t;
        if (i >= S.cb.total8) return;
        int k = 0;
        while (k < 6 && i >= S.cb.beg8[k + 1]) ++k;
        const int j = i - S.cb.beg8[k];
        const float4 v0 = reinterpret_cast<const float4*>(S.cb.s[k])[2 * j];
        const float4 v1 = reinterpret_cast<const float4*>(S.cb.s[k])[2 * j + 1];
        const bf16x8 o = cvt8(v0, v1);
        *(bf16x8*)(S.cb.d[k] + (size_t)j * 8) = o;
    } else if (b < S.nf2b + 1024) {
        const int local = b - S.nf2b;
        const int zz = local >> 8, rem = local & 255;
        const float* __restrict__ src = S.ts[zz];
        unsigned short* __restrict__ dst = S.td[zz];
        const int bx = (rem & 15) * 64, by = (rem >> 4) * 64;
        const int c = t & 63, r0 = t >> 6;
#pragma unroll
        for (int h = 0; h < 16; ++h) {
            const int r = r0 * 16 + h;
            tile[r][c] = src[(size_t)(by + r) * 1024 + bx + c];
        }
        __syncthreads();
#pragma unroll
        for (int h = 0; h < 16; ++h) {
            const int kk = r0 * 16 + h;
            dst[(size_t)(bx + kk) * 1024 + by + c] = f2b(tile[c][kk]);
        }
    } else {
        const int local = b - S.nf2b - 1024;
        const int zz = local >> 10;
        const int idx = (local & 1023) * 256 + t;
        const int o = idx >> 8, j = (idx & 255) * 4;
        const float* W = zz ? S.Wjnt : S.Wrel;
        const float sgn = zz ? -1.f : 1.f;
        unsigned short* rt = zz ? S.UrtVj : S.WrtRel;
        unsigned short* ef = zz ? S.UeffVj : S.WeffRel;
        const float4 w1 = *(const float4*)(W + (size_t)o * 4096 + j);
        const float4 w2 = *(const float4*)(W + (size_t)o * 4096 + 1024 + j);
        const float4 w3 = *(const float4*)(W + (size_t)o * 4096 + 2048 + j);
        const float4 w4 = *(const float4*)(W + (size_t)o * 4096 + 3072 + j);
        us4 tt;
        tt.x = f2b(w1.x + sgn * w4.x); tt.y = f2b(w1.y + sgn * w4.y);
        tt.z = f2b(w1.z + sgn * w4.z); tt.w = f2b(w1.w + sgn * w4.w);
        *(us4*)(rt + (size_t)o * 1024 + j) = tt;
        tt.x = f2b(w2.x - sgn * w4.x); tt.y = f2b(w2.y - sgn * w4.y);
        tt.z = f2b(w2.z - sgn * w4.z); tt.w = f2b(w2.w - sgn * w4.w);
        *(us4*)(ef + (size_t)o * 2048 + j) = tt;
        tt.x = f2b(w3.x); tt.y = f2b(w3.y); tt.z = f2b(w3.z); tt.w = f2b(w3.w);
        *(us4*)(ef + (size_t)o * 2048 + 1024 + j) = tt;
    }
}

// fused softmax + weighted aggregation -> bf16 ctx outputs
__global__ __launch_bounds__(256)
void k_ctx12(const float* __restrict__ relj, const float* __restrict__ s_sbj,
             const float* __restrict__ s_obj, const int* __restrict__ conn,
             unsigned short* __restrict__ ctx1b, unsigned short* __restrict__ ctx2b)
{
    const int bid = blockIdx.x, t = threadIdx.x;
    const float4* relj4 = reinterpret_cast<const float4*>(relj);
    float4 acc = make_float4(0.f, 0.f, 0.f, 0.f);
    if (bid < 64) {
        const int i = bid;
        float sv[16];
        float m = -1e30f;
#pragma unroll
        for (int q = 0; q < 16; ++q) { sv[q] = s_sbj[i * 16 + q]; m = fmaxf(m, sv[q]); }
        float sum = 0.f;
#pragma unroll
        for (int q = 0; q < 16; ++q) { sv[q] = expf(sv[q] - m); sum += sv[q]; }
        const float inv = 1.f / sum;
#pragma unroll
        for (int q = 0; q < 16; ++q) {
            const float w = sv[q] * inv;
            const float4 v = relj4[(size_t)(i * 16 + q) * 256 + t];
            acc.x += w * v.x; acc.y += w * v.y; acc.z += w * v.z; acc.w += w * v.w;
        }
        us4 o; o.x = f2b(acc.x); o.y = f2b(acc.y); o.z = f2b(acc.z); o.w = f2b(acc.w);
        *(us4*)(ctx1b + (size_t)bid * 1024 + t * 4) = o;
    } else {
        const int j = bid - 64;
        __shared__ float sl[64];
        __shared__ int el[64];
        if (t < 64) {
            const int e = conn[t * kN + j];
            el[t] = e;
            sl[t] = (e >= 0) ? s_obj[e] : -1e30f;
        }
        __syncthreads();
        float m = -1e30f;
        for (int i = 0; i < 64; ++i) m = fmaxf(m, sl[i]);
        __syncthreads();
        if (t < 64) sl[t] = (el[t] >= 0) ? expf(sl[t] - m) : 0.f;
        __syncthreads();
        float sum = 0.f;
        for (int i = 0; i < 64; ++i) sum += sl[i];
        const float inv = 1.f / sum;
        for (int i = 0; i < 64; ++i) {
            const int e = el[i];
            if (e >= 0) {
                const float w = sl[i] * inv;
                const float4 v = relj4[(size_t)e * 256 + t];
                acc.x += w * v.x; acc.y += w * v.y; acc.z += w * v.z; acc.w += w * v.w;
            }
        }
        us4 o; o.x = f2b(acc.x); o.y = f2b(acc.y); o.z = f2b(acc.z); o.w = f2b(acc.w);
        *(us4*)(ctx2b + (size_t)j * 1024 + t * 4) = o;
    }
}

// =====================================================================
extern "C" void kernel_launch(void* const* d_in, const int* in_sizes, int n_in,
                              void* d_out, int out_size, void* d_ws, size_t ws_size,
                              hipStream_t stream)
{
    const float* visual   = (const float*)d_in[0];
    const float* relvis   = (const float*)d_in[1];
    const int*   conn     = (const int*)d_in[2];
    const int*   edge_idx = (const int*)d_in[4];
    const float* W_sub    = (const float*)d_in[5];
    const float* W_obj    = (const float*)d_in[6];
    const float* W_r2s    = (const float*)d_in[7];
    const float* W_r2o    = (const float*)d_in[8];
    const float* W_joint  = (const float*)d_in[9];
    const float* W_ctx    = (const float*)d_in[10];
    const float* W_relu   = (const float*)d_in[11];  // (D,3D): Ws|Wo|Wr
    const float* W_relj   = (const float*)d_in[12];
    const float* W_relc   = (const float*)d_in[13];
    const float* W_node   = (const float*)d_in[14];
    const float* b_node   = (const float*)d_in[15];
    const float* W_factor = (const float*)d_in[16];
    (void)in_sizes; (void)n_in; (void)out_size; (void)ws_size;

    float* ws = (float*)d_ws;
    size_t off = 0;
    auto allocF = [&](size_t n) { float* p = ws + off; off += n; return p; };
    auto allocU = [&](size_t n) { return (unsigned short*)allocF((n + 1) / 2); };

    float* partF = allocF((size_t)1024 * 1024);                // f32 partials (skinny)
    unsigned short* partB = allocU((size_t)16 * 1024 * 1024);  // bf16 partials
    float* G0p  = allocF((size_t)4 * 65536);                   // G0 f32 planes (persist)
    unsigned short* R0p = allocU((size_t)4 * 1024 * 1024);     // R0 bf16 planes (persist)
    float* relj  = allocF((size_t)kE * kD);
    float* s_sbj = allocF(kE);
    float* s_obj = allocF(kE);
    unsigned short* relvis_b = allocU((size_t)kE * kD);
    unsigned short* visual_b = allocU((size_t)kN * kD);
    unsigned short* vj_b   = allocU((size_t)kN * kD);
    unsigned short* rj_b   = allocU((size_t)kE * kD);
    unsigned short* relj_b = allocU((size_t)kE * kD);
    unsigned short* rc_bA  = allocU((size_t)kE * kD);
    unsigned short* rc_bB  = allocU((size_t)kE * kD);
    unsigned short* vctx_bA = allocU((size_t)kN * kD);
    unsigned short* vctx_bB = allocU((size_t)kN * kD);
    unsigned short* ctx1_b = allocU((size_t)kN * kD);
    unsigned short* ctx2_b = allocU((size_t)kN * kD);
    unsigned short* Wb_ctx    = allocU((size_t)kD * 3 * kD);
    unsigned short* Wb_relu   = allocU((size_t)kD * 3 * kD);
    unsigned short* Wb_relc   = allocU((size_t)kD * 2 * kD);
    unsigned short* Wb_node   = allocU((size_t)kD * 2 * kD);
    unsigned short* Wb_factor = allocU((size_t)kD * 2 * kD);
    unsigned short* WsubT = allocU((size_t)kD * kD);
    unsigned short* WobjT = allocU((size_t)kD * kD);
    unsigned short* Wr2sT = allocU((size_t)kD * kD);
    unsigned short* Wr2oT = allocU((size_t)kD * kD);
    unsigned short* Wc_s  = allocU((size_t)kD * kD);
    unsigned short* Wc_o  = allocU((size_t)kD * kD);
    unsigned short* WrtRel  = allocU((size_t)kD * kD);      // W1+W4
    unsigned short* WeffRel = allocU((size_t)kD * 2 * kD);  // [W2-W4 | W3]
    unsigned short* UrtVj   = allocU((size_t)kD * kD);      // U1-U4
    unsigned short* UeffVj  = allocU((size_t)kD * 2 * kD);  // [U2+U4 | U3]

    auto seg1 = [](const unsigned short* a) {
        ASrc s; s.s0 = a; s.s1 = nullptr; s.s2 = nullptr; s.mode = 1; return s;
    };
    auto seg2 = [](const unsigned short* a, const unsigned short* b) {
        ASrc s; s.s0 = a; s.s1 = b; s.s2 = nullptr; s.mode = 1; return s;
    };
    auto seg3 = [](const unsigned short* a, const unsigned short* b, const unsigned short* c) {
        ASrc s; s.s0 = a; s.s1 = b; s.s2 = c; s.mode = 1; return s;
    };
    auto prodA = [](const unsigned short* c, const unsigned short* x) {  // [c | c*x]
        ASrc s; s.s0 = c; s.s1 = x; s.s2 = nullptr; s.mode = 2; return s;
    };

    // ---- job-list launch helpers ----
    GJobs G; RJobs R;
    int gn = 0, gt = 0, rn = 0, rtt = 0;
    auto gAdd = [&](ASrc a, const unsigned short* W, int ldw, void* P, int M, int K, int KS, int pbf) {
        G.j[gn].a = a; G.j[gn].W = W; G.j[gn].ldw = ldw; G.j[gn].P = P;
        G.j[gn].M = M; G.j[gn].K = K; G.j[gn].KS = KS; G.j[gn].pbf = pbf;
        G.t0[gn] = gt; gt += KS * (M >> 6) * 8; ++gn;
    };
    auto gLaunch = [&]() {
        G.nj = gn; G.t0[gn] = gt;
        hipLaunchKernelGGL(k_gemm, dim3(gt), dim3(256), 0, stream, G);
        gn = 0; gt = 0;
    };
    auto rAdd = [&](const void* P, int MO8, int KS, int pbf,
                    const void* P2, int KS2, int pbf2,
                    float* Cf, unsigned short* Cb,
                    const unsigned short* addb, const float* bias) {
        R.j[rn].P = P; R.j[rn].MO8 = MO8; R.j[rn].KS = KS; R.j[rn].pbf = pbf;
        R.j[rn].P2 = P2; R.j[rn].KS2 = KS2; R.j[rn].pbf2 = pbf2;
        R.j[rn].Cf = Cf; R.j[rn].Cb = Cb; R.j[rn].addb = addb; R.j[rn].bias = bias;
        R.t0[rn] = rtt; rtt += (MO8 + 255) / 256; ++rn;
    };
    auto rLaunch = [&]() {
        R.nj = rn; R.t0[rn] = rtt;
        hipLaunchKernelGGL(k_reduce, dim3(rtt), dim3(256), 0, stream, R);
        rn = 0; rtt = 0;
    };

    // ---- setup: ONE merged launch (f2b | transpose x4 | buildW) ----
    {
        SetupArgs S;
        const float* srcs[7] = {W_ctx, W_relu, W_relc, W_node, W_factor, relvis, visual};
        unsigned short* dsts[7] = {Wb_ctx, Wb_relu, Wb_relc, Wb_node, Wb_factor, relvis_b, visual_b};
        const int nel[7] = {3 * 1024 * 1024, 3 * 1024 * 1024, 2 * 1024 * 1024,
                            2 * 1024 * 1024, 2 * 1024 * 1024, 1024 * 1024, 64 * 1024};
        int cum = 0;
        for (int k = 0; k < 7; ++k) { S.cb.s[k] = srcs[k]; S.cb.d[k] = dsts[k]; S.cb.beg8[k] = cum; cum += nel[k] / 8; }
        S.cb.total8 = cum;
        S.nf2b = (cum + 255) / 256;
        S.ts[0] = W_sub; S.td[0] = WsubT;
        S.ts[1] = W_obj; S.td[1] = WobjT;
        S.ts[2] = W_r2s; S.td[2] = Wr2sT;
        S.ts[3] = W_r2o; S.td[3] = Wr2oT;
        S.Wrel = W_relj; S.Wjnt = W_joint;
        S.WrtRel = WrtRel; S.WeffRel = WeffRel; S.UrtVj = UrtVj; S.UeffVj = UeffVj;
        hipLaunchKernelGGL(k_setup, dim3(S.nf2b + 1024 + 2048), dim3(256), 0, stream, S);
    }

    const size_t M8 = (size_t)8 * 1024 * 1024;    // bf16 elems
    const size_t M12 = (size_t)12 * 1024 * 1024;

    // ---- T iterations ----
    for (int t = 0; t < kT; ++t) {
        const unsigned short* vcur  = (t == 0) ? visual_b : vctx_bA;
        unsigned short*       vnext = (t == 0) ? vctx_bA : vctx_bB;
        const unsigned short* rccur = (t == 0) ? relvis_b : rc_bA;
        unsigned short*       rcnext = (t == 0) ? rc_bA : rc_bB;

        // L1: vj (f32 KS=8) + rj (bf16 KS=8); iter0 adds Wc_s, Wc_o, R0, G0
        gAdd(prodA(vcur, visual_b), UeffVj, 2048, partF, 64, 2048, 8, 0);
        gAdd(prodA(rccur, relvis_b), WeffRel, 2048, partB, 1024, 2048, 8, 1);
        if (t == 0) {
            gAdd(seg1(Wr2sT), WsubT, 1024, partB + M8,  1024, 1024, 4, 1);   // Wc_s planes
            gAdd(seg1(Wr2oT), WobjT, 1024, partB + M12, 1024, 1024, 4, 1);   // Wc_o planes
            gAdd(seg1(relvis_b), WrtRel, 1024, R0p, 1024, 1024, 4, 1);       // R0 planes
            gAdd(seg1(visual_b), UrtVj, 1024, G0p, 64, 1024, 4, 0);          // G0 planes
        }
        gLaunch();
        // L2: vj = sum(vj planes) + sum(G0 planes) -> bf16
        //     rj = sum(rj planes) + sum(R0 planes) -> bf16 ; iter0: finalize Wc_s/Wc_o
        rAdd(partF, 8192, 8, 0, G0p, 4, 0, nullptr, vj_b, nullptr, nullptr);
        rAdd(partB, 131072, 8, 1, R0p, 4, 1, nullptr, rj_b, nullptr, nullptr);
        if (t == 0) {
            rAdd(partB + M8,  131072, 4, 1, nullptr, 0, 0, nullptr, Wc_s, nullptr, nullptr);
            rAdd(partB + M12, 131072, 4, 1, nullptr, 0, 0, nullptr, Wc_o, nullptr, nullptr);
        }
        rLaunch();

        // L3: asqw partials (4 skinny, f32 KS=2) + relj (bf16 KS=4)
        gAdd(seg1(vj_b), Wb_relu,        3072, partF,          64, 1024, 2, 0);  // a_s planes
        gAdd(seg1(vj_b), Wb_relu + 1024, 3072, partF + 131072, 64, 1024, 2, 0);  // a_o planes
        gAdd(seg1(vj_b), Wc_s,           1024, partF + 262144, 64, 1024, 2, 0);  // qW_s planes
        gAdd(seg1(vj_b), Wc_o,           1024, partF + 393216, 64, 1024, 2, 0);  // qW_o planes
        gAdd(seg1(rj_b), Wb_relu + 2048, 3072, partB,        1024, 1024, 4, 1);  // relj planes
        gLaunch();

        // L4: relj finalize + fused scores (one 512-block kernel)
        hipLaunchKernelGGL(k_relj_sc, dim3(512), dim3(256), 0, stream,
                           partB, 4, partF, partF + 262144, partF + 393216,
                           edge_idx, relj, relj_b, s_sbj, s_obj);

        // softmax + aggregation (bf16 ctx out)
        hipLaunchKernelGGL(k_ctx12, dim3(128), dim3(256), 0, stream,
                           relj, s_sbj, s_obj, conn, ctx1_b, ctx2_b);

        // L7: vctx' + rc'
        gAdd(seg3(vcur, ctx1_b, ctx2_b), Wb_ctx, 3072, partF, 64, 3072, 8, 0);
        gAdd(seg2(rccur, relj_b), Wb_relc, 2048, partB, 1024, 2048, 8, 1);
        gLaunch();
        // L8
        rAdd(partF, 8192, 8, 0, nullptr, 0, 0, nullptr, vnext, nullptr, nullptr);
        rAdd(partB, 131072, 8, 1, nullptr, 0, 0, nullptr, rcnext, nullptr, nullptr);
        rLaunch();
    }

    float* rel_out = (float*)d_out;
    float* v_out   = (float*)d_out + (size_t)kE * kD;
    // F1: rel_out (bf16 partials KS=4) + v_out (f32 partials KS=8, skinny)
    gAdd(seg2(relvis_b, rc_bB), Wb_factor, 2048, partB, 1024, 2048, 4, 1);
    gAdd(seg2(visual_b, vctx_bB), Wb_node, 2048, partF, 64, 2048, 8, 0);
    gLaunch();
    // F2
    rAdd(partB, 131072, 4, 1, nullptr, 0, 0, rel_out, nullptr, nullptr, nullptr);
    rAdd(partF, 8192, 8, 0, nullptr, 0, 0, v_out, nullptr, nullptr, b_node);
    rLaunch();
}

// Round 16
// 205.536 us; speedup vs baseline: 2.9497x; 1.0032x over previous
//
#include <hip/hip_runtime.h>

// ---- problem constants ----
static constexpr int kN = 64;    // nodes
static constexpr int kD = 1024;  // feature dim
static constexpr int kE = 1024;  // edges (16 per row, row-major by (i,j))
static constexpr int kT = 2;     // iterations

typedef short  bf16x8 __attribute__((ext_vector_type(8)));
typedef float  f32x4  __attribute__((ext_vector_type(4)));
typedef unsigned short us8 __attribute__((ext_vector_type(8)));
typedef unsigned short us4 __attribute__((ext_vector_type(4)));

__device__ __forceinline__ unsigned short f2b(float f) {
    unsigned int u = __builtin_bit_cast(unsigned int, f);
    u += 0x7FFFu + ((u >> 16) & 1u);          // RNE
    return (unsigned short)(u >> 16);
}
__device__ __forceinline__ float b2f(unsigned short u) {
    unsigned int x = ((unsigned int)u) << 16;
    return __builtin_bit_cast(float, x);
}
__device__ __forceinline__ bf16x8 cvt8(float4 a, float4 b) {
    us8 o;
    o[0] = f2b(a.x); o[1] = f2b(a.y); o[2] = f2b(a.z); o[3] = f2b(a.w);
    o[4] = f2b(b.x); o[5] = f2b(b.y); o[6] = f2b(b.z); o[7] = f2b(b.w);
    return __builtin_bit_cast(bf16x8, o);
}

// A-operand source, ALL bf16 [row][1024] segments:
// mode 1: concat of segments s0|s1|s2 ; mode 2: [s0 | s0*s1]
struct ASrc { const unsigned short* s0; const unsigned short* s1; const unsigned short* s2; int mode; };

__device__ __forceinline__ bf16x8 loadA8(const ASrc& s, int row, int kg) {
    const int seg = kg >> 10, k = kg & 1023;
    const size_t ro = (size_t)row * 1024 + k;
    if (s.mode == 1) {
        const unsigned short* p = (seg == 0) ? s.s0 : (seg == 1 ? s.s1 : s.s2);
        return *(const bf16x8*)(p + ro);
    }
    const bf16x8 a = *(const bf16x8*)(s.s0 + ro);
    if (seg == 0) return a;
    const bf16x8 b = *(const bf16x8*)(s.s1 + ro);
    const us8 ua = __builtin_bit_cast(us8, a), ub = __builtin_bit_cast(us8, b);
    us8 o;
#pragma unroll
    for (int q = 0; q < 8; ++q) o[q] = f2b(b2f(ua[q]) * b2f(ub[q]));
    return __builtin_bit_cast(bf16x8, o);
}

// =====================================================================
// Job-list MFMA GEMM: uniform 64-row x 128-col tile, 4 waves (2x2), BK=64.
// A+B staged via swizzled LDS. pbf: bf16 partials via LDS-coalesced
// epilogue; else f32 direct. Row-tile fastest -> XCD-affine A reuse.
// NO device-scope fences (R12 lesson: __threadfence costs ~100us at scale).
// =====================================================================
struct GJob { ASrc a; const unsigned short* W; int ldw; void* P; int M; int K; int KS; int pbf; };
struct GJobs { GJob j[6]; int t0[7]; int nj; };

__global__ __launch_bounds__(256)
void k_gemm(GJobs G)
{
    __shared__ unsigned short lds[12288];   // As[64][64] | Bs[128][64]; epi Cs[64][132]
    const int flat = blockIdx.x;
    int ji = 0;
    while (ji + 1 < G.nj && flat >= G.t0[ji + 1]) ++ji;
    const GJob J = G.j[ji];
    const int local = flat - G.t0[ji];
    const int rowTiles = J.M >> 6;
    const int rt = local & (rowTiles - 1);          // fastest -> XCD affinity
    const int rest = local / rowTiles;
    const int ct = rest & 7, z = rest >> 3;
    const int rowBase = rt * 64, colBase = ct * 128;
    const int kchunk = J.K / J.KS, kbeg = z * kchunk, kend = kbeg + kchunk;

    const int tid = threadIdx.x, lane = tid & 63, wid = tid >> 6;
    const int l15 = lane & 15, l4 = lane >> 4;
    const int sr = tid >> 3, sc8 = tid & 7;
    const int wc8 = (sc8 ^ (sr & 7)) * 8;
    const int wr = wid >> 1, wc = wid & 1;

    bf16x8 ra[2], rb[4];
    auto stage = [&](int kt) {
#pragma unroll
        for (int h = 0; h < 2; ++h)
            ra[h] = loadA8(J.a, rowBase + sr + 32 * h, kt + sc8 * 8);
#pragma unroll
        for (int h = 0; h < 4; ++h)
            rb[h] = *(const bf16x8*)(J.W + (size_t)(colBase + sr + 32 * h) * J.ldw + kt + sc8 * 8);
    };

    f32x4 acc[2][4] = {};
    stage(kbeg);
    for (int kt = kbeg; kt < kend; kt += 64) {
        __syncthreads();
#pragma unroll
        for (int h = 0; h < 2; ++h)
            *(bf16x8*)&lds[(sr + 32 * h) * 64 + wc8] = ra[h];
#pragma unroll
        for (int h = 0; h < 4; ++h)
            *(bf16x8*)&lds[4096 + (sr + 32 * h) * 64 + wc8] = rb[h];
        __syncthreads();
        if (kt + 64 < kend) stage(kt + 64);
#pragma unroll
        for (int kk = 0; kk < 2; ++kk) {
            const int c8 = kk * 4 + l4;
            bf16x8 af[2], bv[4];
#pragma unroll
            for (int m = 0; m < 2; ++m) {
                const int ar = wr * 32 + m * 16 + l15;
                af[m] = *(const bf16x8*)&lds[ar * 64 + (c8 ^ (ar & 7)) * 8];
            }
#pragma unroll
            for (int n = 0; n < 4; ++n) {
                const int br = wc * 64 + n * 16 + l15;
                bv[n] = *(const bf16x8*)&lds[4096 + br * 64 + (c8 ^ (br & 7)) * 8];
            }
#pragma unroll
            for (int m = 0; m < 2; ++m)
#pragma unroll
                for (int n = 0; n < 4; ++n)
                    acc[m][n] = __builtin_amdgcn_mfma_f32_16x16x32_bf16(af[m], bv[n], acc[m][n], 0, 0, 0);
        }
    }

    if (J.pbf) {
        __syncthreads();
#pragma unroll
        for (int m = 0; m < 2; ++m)
#pragma unroll
            for (int n = 0; n < 4; ++n)
#pragma unroll
                for (int r = 0; r < 4; ++r)
                    lds[(wr * 32 + m * 16 + l4 * 4 + r) * 132 + wc * 64 + n * 16 + l15] =
                        f2b(acc[m][n][r]);
        __syncthreads();
        unsigned short* Pb = (unsigned short*)J.P + (size_t)z * J.M * 1024;
#pragma unroll
        for (int c = tid; c < 1024; c += 256) {
            const int row = c >> 4, ch = c & 15;
            *(bf16x8*)(Pb + (size_t)(rowBase + row) * 1024 + colBase + ch * 8) =
                *(const bf16x8*)&lds[row * 132 + ch * 8];
        }
    } else {
        float* base = (float*)J.P + (size_t)z * J.M * 1024;
#pragma unroll
        for (int m = 0; m < 2; ++m) {
            const int row = rowBase + wr * 32 + m * 16 + l4 * 4;
#pragma unroll
            for (int n = 0; n < 4; ++n) {
                const int col = colBase + wc * 64 + n * 16 + l15;
#pragma unroll
                for (int r = 0; r < 4; ++r)
                    base[(size_t)(row + r) * 1024 + col] = acc[m][n][r];
            }
        }
    }
}

// =====================================================================
// Job-list split-K reduce, 8-elem granularity.
// Normal job: out = sum planes of P (KS, pbf) [+ planes of P2 (KS2, pbf2)]
//             (+addb bf16) (+bias)
// Conversion job (csrc != null): Cb[i8*8..] = bf16(csrc[i8*8..])
// =====================================================================
struct RJob { const void* P; int MO8; int KS; int pbf;
              const void* P2; int KS2; int pbf2;
              float* Cf; unsigned short* Cb;
              const unsigned short* addb; const float* bias;
              const float* csrc; };
struct RJobs { RJob j[10]; int t0[11]; int nj; };

__global__ void k_reduce(RJobs R)
{
    const int flat = blockIdx.x;
    int ji = 0;
    while (ji + 1 < R.nj && flat >= R.t0[ji + 1]) ++ji;
    const RJob J = R.j[ji];
    const int i8 = (flat - R.t0[ji]) * 256 + threadIdx.x;
    if (i8 >= J.MO8) return;
    if (J.csrc) {       // streaming f32 -> bf16 conversion job
        const float4 v0 = reinterpret_cast<const float4*>(J.csrc)[2 * i8];
        const float4 v1 = reinterpret_cast<const float4*>(J.csrc)[2 * i8 + 1];
        *(bf16x8*)(J.Cb + (size_t)i8 * 8) = cvt8(v0, v1);
        return;
    }
    float s[8] = {0.f, 0.f, 0.f, 0.f, 0.f, 0.f, 0.f, 0.f};
    if (J.pbf) {
        const unsigned short* P = (const unsigned short*)J.P;
        for (int z = 0; z < J.KS; ++z) {
            const us8 v = *(const us8*)(P + (size_t)z * J.MO8 * 8 + (size_t)i8 * 8);
#pragma unroll
            for (int q = 0; q < 8; ++q) s[q] += b2f(v[q]);
        }
    } else {
        const float* P = (const float*)J.P;
        for (int z = 0; z < J.KS; ++z) {
            const float* p = P + (size_t)z * J.MO8 * 8 + (size_t)i8 * 8;
            const float4 v0 = *(const float4*)p;
            const float4 v1 = *(const float4*)(p + 4);
            s[0] += v0.x; s[1] += v0.y; s[2] += v0.z; s[3] += v0.w;
            s[4] += v1.x; s[5] += v1.y; s[6] += v1.z; s[7] += v1.w;
        }
    }
    if (J.P2) {
        if (J.pbf2) {
            const unsigned short* P = (const unsigned short*)J.P2;
            for (int z = 0; z < J.KS2; ++z) {
                const us8 v = *(const us8*)(P + (size_t)z * J.MO8 * 8 + (size_t)i8 * 8);
#pragma unroll
                for (int q = 0; q < 8; ++q) s[q] += b2f(v[q]);
            }
        } else {
            const float* P = (const float*)J.P2;
            for (int z = 0; z < J.KS2; ++z) {
                const float* p = P + (size_t)z * J.MO8 * 8 + (size_t)i8 * 8;
                const float4 v0 = *(const float4*)p;
                const float4 v1 = *(const float4*)(p + 4);
                s[0] += v0.x; s[1] += v0.y; s[2] += v0.z; s[3] += v0.w;
                s[4] += v1.x; s[5] += v1.y; s[6] += v1.z; s[7] += v1.w;
            }
        }
    }
    if (J.addb) {
        const us8 v = *(const us8*)(J.addb + (size_t)i8 * 8);
#pragma unroll
        for (int q = 0; q < 8; ++q) s[q] += b2f(v[q]);
    }
    if (J.bias) {
        const int c8 = i8 & 127;
#pragma unroll
        for (int q = 0; q < 8; ++q) s[q] += J.bias[c8 * 8 + q];
    }
    if (J.Cf) {
        *(float4*)(J.Cf + (size_t)i8 * 8)     = make_float4(s[0], s[1], s[2], s[3]);
        *(float4*)(J.Cf + (size_t)i8 * 8 + 4) = make_float4(s[4], s[5], s[6], s[7]);
    }
    if (J.Cb) {
        us8 o;
#pragma unroll
        for (int q = 0; q < 8; ++q) o[q] = f2b(s[q]);
        *(us8*)(J.Cb + (size_t)i8 * 8) = o;
    }
}

// =====================================================================
// relj finalize + fused scores. Grid 512 x 256: block = 2 edges.
// =====================================================================
__global__ __launch_bounds__(256)
void k_relj_sc(const unsigned short* __restrict__ P, int KS,
               const float* __restrict__ gA,     // a_s planes; a_o at +131072; z-stride 65536
               const float* __restrict__ qsP,    // qW_s planes (2, z-stride 65536)
               const float* __restrict__ qoP,    // qW_o planes
               const int* __restrict__ eidx,
               float* __restrict__ Cf, unsigned short* __restrict__ Cb,
               float* __restrict__ s_sbj, float* __restrict__ s_obj)
{
    __shared__ float wred[8];
    const int t = threadIdx.x;
    const int i8 = blockIdx.x * 256 + t;
    float s[8] = {0.f, 0.f, 0.f, 0.f, 0.f, 0.f, 0.f, 0.f};
    for (int z = 0; z < KS; ++z) {
        const us8 v = *(const us8*)(P + (size_t)z * 1048576 + (size_t)i8 * 8);
#pragma unroll
        for (int q = 0; q < 8; ++q) s[q] += b2f(v[q]);
    }
    const int e = i8 >> 7, c8 = i8 & 127;
    const int idx = eidx[e];
    const int in_ = idx >> 6, jn = idx & 63;
    const float* as_ = gA + (size_t)in_ * 1024 + c8 * 8;
    const float* ao_ = gA + 131072 + (size_t)jn * 1024 + c8 * 8;
    for (int z = 0; z < 2; ++z) {
#pragma unroll
        for (int q = 0; q < 8; ++q)
            s[q] += as_[(size_t)z * 65536 + q] + ao_[(size_t)z * 65536 + q];
    }
    *(float4*)(Cf + (size_t)i8 * 8)     = make_float4(s[0], s[1], s[2], s[3]);
    *(float4*)(Cf + (size_t)i8 * 8 + 4) = make_float4(s[4], s[5], s[6], s[7]);
    us8 o;
#pragma unroll
    for (int q = 0; q < 8; ++q) o[q] = f2b(s[q]);
    *(us8*)(Cb + (size_t)i8 * 8) = o;
    float qs[8] = {0.f, 0.f, 0.f, 0.f, 0.f, 0.f, 0.f, 0.f};
    float qo[8] = {0.f, 0.f, 0.f, 0.f, 0.f, 0.f, 0.f, 0.f};
    const float* qsp = qsP + (size_t)in_ * 1024 + c8 * 8;
    const float* qop = qoP + (size_t)jn * 1024 + c8 * 8;
    for (int z = 0; z < 2; ++z) {
#pragma unroll
        for (int q = 0; q < 8; ++q) {
            qs[q] += qsp[(size_t)z * 65536 + q];
            qo[q] += qop[(size_t)z * 65536 + q];
        }
    }
    float vs = 0.f, vo = 0.f;
#pragma unroll
    for (int q = 0; q < 8; ++q) { vs += s[q] * qs[q]; vo += s[q] * qo[q]; }
    for (int off = 32; off; off >>= 1) {
        vs += __shfl_down(vs, off);
        vo += __shfl_down(vo, off);
    }
    const int wid = t >> 6;
    if ((t & 63) == 0) { wred[wid] = vs; wred[4 + wid] = vo; }
    __syncthreads();
    if (t == 0) {
        s_sbj[e] = (wred[0] + wred[1]) * 0.03125f;
        s_obj[e] = (wred[4] + wred[5]) * 0.03125f;
    } else if (t == 128) {
        s_sbj[e] = (wred[2] + wred[3]) * 0.03125f;
        s_obj[e] = (wred[6] + wred[7]) * 0.03125f;
    }
}

// =====================================================================
// critical setup: {relvis, visual} f2b | 4x transpose | buildW (one launch)
// (big weight conversions deferred into L2-iter0 as k_reduce conv jobs)
// =====================================================================
struct ConvBatch { const float* s[2]; unsigned short* d[2]; int beg8[2]; int total8; };
struct SetupArgs {
    ConvBatch cb; int nf2b;
    const float* ts[4]; unsigned short* td[4];
    const float* Wrel; const float* Wjnt;
    unsigned short *WrtRel, *WeffRel, *UrtVj, *UeffVj;
};

__global__ __launch_bounds__(256)
void k_setup(SetupArgs S)
{
    __shared__ float tile[64][65];
    const int b = blockIdx.x, t = threadIdx.x;
    if (b < S.nf2b) {
        const int i = b * 256 + t;
        if (i >= S.cb.total8) return;
        int k = 0;
        while (k < 1 && i >= S.cb.beg8[k + 1]) ++k;
        const int j = i - S.cb.beg8[k];
        const float4 v0 = reinterpret_cast<const float4*>(S.cb.s[k])[2 * j];
        const float4 v1 = reinterpret_cast<const float4*>(S.cb.s[k])[2 * j + 1];
        const bf16x8 o = cvt8(v0, v1);
        *(bf16x8*)(S.cb.d[k] + (size_t)j * 8) = o;
    } else if (b < S.nf2b + 1024) {
        const int local = b - S.nf2b;
        const int zz = local >> 8, rem = local & 255;
        const float* __restrict__ src = S.ts[zz];
        unsigned short* __restrict__ dst = S.td[zz];
        const int bx = (rem & 15) * 64, by = (rem >> 4) * 64;
        const int c = t & 63, r0 = t >> 6;
#pragma unroll
        for (int h = 0; h < 16; ++h) {
            const int r = r0 * 16 + h;
            tile[r][c] = src[(size_t)(by + r) * 1024 + bx + c];
        }
        __syncthreads();
#pragma unroll
        for (int h = 0; h < 16; ++h) {
            const int kk = r0 * 16 + h;
            dst[(size_t)(bx + kk) * 1024 + by + c] = f2b(tile[c][kk]);
        }
    } else {
        const int local = b - S.nf2b - 1024;
        const int zz = local >> 10;
        const int idx = (local & 1023) * 256 + t;
        const int o = idx >> 8, j = (idx & 255) * 4;
        const float* W = zz ? S.Wjnt : S.Wrel;
        const float sgn = zz ? -1.f : 1.f;
        unsigned short* rt = zz ? S.UrtVj : S.WrtRel;
        unsigned short* ef = zz ? S.UeffVj : S.WeffRel;
        const float4 w1 = *(const float4*)(W + (size_t)o * 4096 + j);
        const float4 w2 = *(const float4*)(W + (size_t)o * 4096 + 1024 + j);
        const float4 w3 = *(const float4*)(W + (size_t)o * 4096 + 2048 + j);
        const float4 w4 = *(const float4*)(W + (size_t)o * 4096 + 3072 + j);
        us4 tt;
        tt.x = f2b(w1.x + sgn * w4.x); tt.y = f2b(w1.y + sgn * w4.y);
        tt.z = f2b(w1.z + sgn * w4.z); tt.w = f2b(w1.w + sgn * w4.w);
        *(us4*)(rt + (size_t)o * 1024 + j) = tt;
        tt.x = f2b(w2.x - sgn * w4.x); tt.y = f2b(w2.y - sgn * w4.y);
        tt.z = f2b(w2.z - sgn * w4.z); tt.w = f2b(w2.w - sgn * w4.w);
        *(us4*)(ef + (size_t)o * 2048 + j) = tt;
        tt.x = f2b(w3.x); tt.y = f2b(w3.y); tt.z = f2b(w3.z); tt.w = f2b(w3.w);
        *(us4*)(ef + (size_t)o * 2048 + 1024 + j) = tt;
    }
}

// fused softmax + weighted aggregation -> bf16 ctx outputs
__global__ __launch_bounds__(256)
void k_ctx12(const float* __restrict__ relj, const float* __restrict__ s_sbj,
             const float* __restrict__ s_obj, const int* __restrict__ conn,
             unsigned short* __restrict__ ctx1b, unsigned short* __restrict__ ctx2b)
{
    const int bid = blockIdx.x, t = threadIdx.x;
    const float4* relj4 = reinterpret_cast<const float4*>(relj);
    float4 acc = make_float4(0.f, 0.f, 0.f, 0.f);
    if (bid < 64) {
        const int i = bid;
        float sv[16];
        float m = -1e30f;
#pragma unroll
        for (int q = 0; q < 16; ++q) { sv[q] = s_sbj[i * 16 + q]; m = fmaxf(m, sv[q]); }
        float sum = 0.f;
#pragma unroll
        for (int q = 0; q < 16; ++q) { sv[q] = expf(sv[q] - m); sum += sv[q]; }
        const float inv = 1.f / sum;
#pragma unroll
        for (int q = 0; q < 16; ++q) {
            const float w = sv[q] * inv;
            const float4 v = relj4[(size_t)(i * 16 + q) * 256 + t];
            acc.x += w * v.x; acc.y += w * v.y; acc.z += w * v.z; acc.w += w * v.w;
        }
        us4 o; o.x = f2b(acc.x); o.y = f2b(acc.y); o.z = f2b(acc.z); o.w = f2b(acc.w);
        *(us4*)(ctx1b + (size_t)bid * 1024 + t * 4) = o;
    } else {
        const int j = bid - 64;
        __shared__ float sl[64];
        __shared__ int el[64];
        if (t < 64) {
            const int e = conn[t * kN + j];
            el[t] = e;
            sl[t] = (e >= 0) ? s_obj[e] : -1e30f;
        }
        __syncthreads();
        float m = -1e30f;
        for (int i = 0; i < 64; ++i) m = fmaxf(m, sl[i]);
        __syncthreads();
        if (t < 64) sl[t] = (el[t] >= 0) ? expf(sl[t] - m) : 0.f;
        __syncthreads();
        float sum = 0.f;
        for (int i = 0; i < 64; ++i) sum += sl[i];
        const float inv = 1.f / sum;
        for (int i = 0; i < 64; ++i) {
            const int e = el[i];
            if (e >= 0) {
                const float w = sl[i] * inv;
                const float4 v = relj4[(size_t)e * 256 + t];
                acc.x += w * v.x; acc.y += w * v.y; acc.z += w * v.z; acc.w += w * v.w;
            }
        }
        us4 o; o.x = f2b(acc.x); o.y = f2b(acc.y); o.z = f2b(acc.z); o.w = f2b(acc.w);
        *(us4*)(ctx2b + (size_t)j * 1024 + t * 4) = o;
    }
}

// =====================================================================
extern "C" void kernel_launch(void* const* d_in, const int* in_sizes, int n_in,
                              void* d_out, int out_size, void* d_ws, size_t ws_size,
                              hipStream_t stream)
{
    const float* visual   = (const float*)d_in[0];
    const float* relvis   = (const float*)d_in[1];
    const int*   conn     = (const int*)d_in[2];
    const int*   edge_idx = (const int*)d_in[4];
    const float* W_sub    = (const float*)d_in[5];
    const float* W_obj    = (const float*)d_in[6];
    const float* W_r2s    = (const float*)d_in[7];
    const float* W_r2o    = (const float*)d_in[8];
    const float* W_joint  = (const float*)d_in[9];
    const float* W_ctx    = (const float*)d_in[10];
    const float* W_relu   = (const float*)d_in[11];  // (D,3D): Ws|Wo|Wr
    const float* W_relj   = (const float*)d_in[12];
    const float* W_relc   = (const float*)d_in[13];
    const float* W_node   = (const float*)d_in[14];
    const float* b_node   = (const float*)d_in[15];
    const float* W_factor = (const float*)d_in[16];
    (void)in_sizes; (void)n_in; (void)out_size; (void)ws_size;

    float* ws = (float*)d_ws;
    size_t off = 0;
    auto allocF = [&](size_t n) { float* p = ws + off; off += n; return p; };
    auto allocU = [&](size_t n) { return (unsigned short*)allocF((n + 1) / 2); };

    float* partF = allocF((size_t)1024 * 1024);                // f32 partials (skinny)
    unsigned short* partB = allocU((size_t)16 * 1024 * 1024);  // bf16 partials
    float* G0p  = allocF((size_t)4 * 65536);                   // G0 f32 planes (persist)
    unsigned short* R0p = allocU((size_t)4 * 1024 * 1024);     // R0 bf16 planes (persist)
    float* relj  = allocF((size_t)kE * kD);
    float* s_sbj = allocF(kE);
    float* s_obj = allocF(kE);
    unsigned short* relvis_b = allocU((size_t)kE * kD);
    unsigned short* visual_b = allocU((size_t)kN * kD);
    unsigned short* vj_b   = allocU((size_t)kN * kD);
    unsigned short* rj_b   = allocU((size_t)kE * kD);
    unsigned short* relj_b = allocU((size_t)kE * kD);
    unsigned short* rc_bA  = allocU((size_t)kE * kD);
    unsigned short* rc_bB  = allocU((size_t)kE * kD);
    unsigned short* vctx_bA = allocU((size_t)kN * kD);
    unsigned short* vctx_bB = allocU((size_t)kN * kD);
    unsigned short* ctx1_b = allocU((size_t)kN * kD);
    unsigned short* ctx2_b = allocU((size_t)kN * kD);
    unsigned short* Wb_ctx    = allocU((size_t)kD * 3 * kD);
    unsigned short* Wb_relu   = allocU((size_t)kD * 3 * kD);
    unsigned short* Wb_relc   = allocU((size_t)kD * 2 * kD);
    unsigned short* Wb_node   = allocU((size_t)kD * 2 * kD);
    unsigned short* Wb_factor = allocU((size_t)kD * 2 * kD);
    unsigned short* WsubT = allocU((size_t)kD * kD);
    unsigned short* WobjT = allocU((size_t)kD * kD);
    unsigned short* Wr2sT = allocU((size_t)kD * kD);
    unsigned short* Wr2oT = allocU((size_t)kD * kD);
    unsigned short* Wc_s  = allocU((size_t)kD * kD);
    unsigned short* Wc_o  = allocU((size_t)kD * kD);
    unsigned short* WrtRel  = allocU((size_t)kD * kD);      // W1+W4
    unsigned short* WeffRel = allocU((size_t)kD * 2 * kD);  // [W2-W4 | W3]
    unsigned short* UrtVj   = allocU((size_t)kD * kD);      // U1-U4
    unsigned short* UeffVj  = allocU((size_t)kD * 2 * kD);  // [U2+U4 | U3]

    auto seg1 = [](const unsigned short* a) {
        ASrc s; s.s0 = a; s.s1 = nullptr; s.s2 = nullptr; s.mode = 1; return s;
    };
    auto seg2 = [](const unsigned short* a, const unsigned short* b) {
        ASrc s; s.s0 = a; s.s1 = b; s.s2 = nullptr; s.mode = 1; return s;
    };
    auto seg3 = [](const unsigned short* a, const unsigned short* b, const unsigned short* c) {
        ASrc s; s.s0 = a; s.s1 = b; s.s2 = c; s.mode = 1; return s;
    };
    auto prodA = [](const unsigned short* c, const unsigned short* x) {  // [c | c*x]
        ASrc s; s.s0 = c; s.s1 = x; s.s2 = nullptr; s.mode = 2; return s;
    };

    // ---- job-list launch helpers ----
    GJobs G; RJobs R;
    int gn = 0, gt = 0, rn = 0, rtt = 0;
    auto gAdd = [&](ASrc a, const unsigned short* W, int ldw, void* P, int M, int K, int KS, int pbf) {
        G.j[gn].a = a; G.j[gn].W = W; G.j[gn].ldw = ldw; G.j[gn].P = P;
        G.j[gn].M = M; G.j[gn].K = K; G.j[gn].KS = KS; G.j[gn].pbf = pbf;
        G.t0[gn] = gt; gt += KS * (M >> 6) * 8; ++gn;
    };
    auto gLaunch = [&]() {
        G.nj = gn; G.t0[gn] = gt;
        hipLaunchKernelGGL(k_gemm, dim3(gt), dim3(256), 0, stream, G);
        gn = 0; gt = 0;
    };
    auto rAdd = [&](const void* P, int MO8, int KS, int pbf,
                    const void* P2, int KS2, int pbf2,
                    float* Cf, unsigned short* Cb,
                    const unsigned short* addb, const float* bias) {
        R.j[rn].P = P; R.j[rn].MO8 = MO8; R.j[rn].KS = KS; R.j[rn].pbf = pbf;
        R.j[rn].P2 = P2; R.j[rn].KS2 = KS2; R.j[rn].pbf2 = pbf2;
        R.j[rn].Cf = Cf; R.j[rn].Cb = Cb; R.j[rn].addb = addb; R.j[rn].bias = bias;
        R.j[rn].csrc = nullptr;
        R.t0[rn] = rtt; rtt += (MO8 + 255) / 256; ++rn;
    };
    auto rConv = [&](const float* src, unsigned short* dst, int MO8) {
        R.j[rn].P = nullptr; R.j[rn].MO8 = MO8; R.j[rn].KS = 0; R.j[rn].pbf = 0;
        R.j[rn].P2 = nullptr; R.j[rn].KS2 = 0; R.j[rn].pbf2 = 0;
        R.j[rn].Cf = nullptr; R.j[rn].Cb = dst; R.j[rn].addb = nullptr; R.j[rn].bias = nullptr;
        R.j[rn].csrc = src;
        R.t0[rn] = rtt; rtt += (MO8 + 255) / 256; ++rn;
    };
    auto rLaunch = [&]() {
        R.nj = rn; R.t0[rn] = rtt;
        hipLaunchKernelGGL(k_reduce, dim3(rtt), dim3(256), 0, stream, R);
        rn = 0; rtt = 0;
    };

    // ---- critical setup: ONE launch ({relvis, visual} f2b | transpose | buildW) ----
    {
        SetupArgs S;
        S.cb.s[0] = relvis; S.cb.d[0] = relvis_b; S.cb.beg8[0] = 0;
        S.cb.s[1] = visual; S.cb.d[1] = visual_b; S.cb.beg8[1] = 1024 * 1024 / 8;
        S.cb.total8 = 1024 * 1024 / 8 + 64 * 1024 / 8;
        S.nf2b = (S.cb.total8 + 255) / 256;
        S.ts[0] = W_sub; S.td[0] = WsubT;
        S.ts[1] = W_obj; S.td[1] = WobjT;
        S.ts[2] = W_r2s; S.td[2] = Wr2sT;
        S.ts[3] = W_r2o; S.td[3] = Wr2oT;
        S.Wrel = W_relj; S.Wjnt = W_joint;
        S.WrtRel = WrtRel; S.WeffRel = WeffRel; S.UrtVj = UrtVj; S.UeffVj = UeffVj;
        hipLaunchKernelGGL(k_setup, dim3(S.nf2b + 1024 + 2048), dim3(256), 0, stream, S);
    }

    const size_t M8 = (size_t)8 * 1024 * 1024;    // bf16 elems
    const size_t M12 = (size_t)12 * 1024 * 1024;

    // ---- T iterations ----
    for (int t = 0; t < kT; ++t) {
        const unsigned short* vcur  = (t == 0) ? visual_b : vctx_bA;
        unsigned short*       vnext = (t == 0) ? vctx_bA : vctx_bB;
        const unsigned short* rccur = (t == 0) ? relvis_b : rc_bA;
        unsigned short*       rcnext = (t == 0) ? rc_bA : rc_bB;

        // L1: vj (f32 KS=8) + rj (bf16 KS=8); iter0 adds Wc_s, Wc_o, R0, G0
        gAdd(prodA(vcur, visual_b), UeffVj, 2048, partF, 64, 2048, 8, 0);
        gAdd(prodA(rccur, relvis_b), WeffRel, 2048, partB, 1024, 2048, 8, 1);
        if (t == 0) {
            gAdd(seg1(Wr2sT), WsubT, 1024, partB + M8,  1024, 1024, 4, 1);   // Wc_s planes
            gAdd(seg1(Wr2oT), WobjT, 1024, partB + M12, 1024, 1024, 4, 1);   // Wc_o planes
            gAdd(seg1(relvis_b), WrtRel, 1024, R0p, 1024, 1024, 4, 1);       // R0 planes
            gAdd(seg1(visual_b), UrtVj, 1024, G0p, 64, 1024, 4, 0);          // G0 planes
        }
        gLaunch();
        // L2: vj/rj reduces (+G0/R0 planes); iter0 also: Wc finalize + deferred weight convs
        rAdd(partF, 8192, 8, 0, G0p, 4, 0, nullptr, vj_b, nullptr, nullptr);
        rAdd(partB, 131072, 8, 1, R0p, 4, 1, nullptr, rj_b, nullptr, nullptr);
        if (t == 0) {
            rAdd(partB + M8,  131072, 4, 1, nullptr, 0, 0, nullptr, Wc_s, nullptr, nullptr);
            rAdd(partB + M12, 131072, 4, 1, nullptr, 0, 0, nullptr, Wc_o, nullptr, nullptr);
            rConv(W_relu,   Wb_relu,   3 * 1024 * 1024 / 8);
            rConv(W_ctx,    Wb_ctx,    3 * 1024 * 1024 / 8);
            rConv(W_relc,   Wb_relc,   2 * 1024 * 1024 / 8);
            rConv(W_node,   Wb_node,   2 * 1024 * 1024 / 8);
            rConv(W_factor, Wb_factor, 2 * 1024 * 1024 / 8);
        }
        rLaunch();

        // L3: asqw partials (4 skinny, f32 KS=2) + relj (bf16 KS=4)
        gAdd(seg1(vj_b), Wb_relu,        3072, partF,          64, 1024, 2, 0);  // a_s planes
        gAdd(seg1(vj_b), Wb_relu + 1024, 3072, partF + 131072, 64, 1024, 2, 0);  // a_o planes
        gAdd(seg1(vj_b), Wc_s,           1024, partF + 262144, 64, 1024, 2, 0);  // qW_s planes
        gAdd(seg1(vj_b), Wc_o,           1024, partF + 393216, 64, 1024, 2, 0);  // qW_o planes
        gAdd(seg1(rj_b), Wb_relu + 2048, 3072, partB,        1024, 1024, 4, 1);  // relj planes
        gLaunch();

        // L4: relj finalize + fused scores (one 512-block kernel)
        hipLaunchKernelGGL(k_relj_sc, dim3(512), dim3(256), 0, stream,
                           partB, 4, partF, partF + 262144, partF + 393216,
                           edge_idx, relj, relj_b, s_sbj, s_obj);

        // softmax + aggregation (bf16 ctx out)
        hipLaunchKernelGGL(k_ctx12, dim3(128), dim3(256), 0, stream,
                           relj, s_sbj, s_obj, conn, ctx1_b, ctx2_b);

        // L7: vctx' + rc'
        gAdd(seg3(vcur, ctx1_b, ctx2_b), Wb_ctx, 3072, partF, 64, 3072, 8, 0);
        gAdd(seg2(rccur, relj_b), Wb_relc, 2048, partB, 1024, 2048, 8, 1);
        gLaunch();
        // L8
        rAdd(partF, 8192, 8, 0, nullptr, 0, 0, nullptr, vnext, nullptr, nullptr);
        rAdd(partB, 131072, 8, 1, nullptr, 0, 0, nullptr, rcnext, nullptr, nullptr);
        rLaunch();
    }

    float* rel_out = (float*)d_out;
    float* v_out   = (float*)d_out + (size_t)kE * kD;
    // F1: rel_out (bf16 partials KS=4) + v_out (f32 partials KS=8, skinny)
    gAdd(seg2(relvis_b, rc_bB), Wb_factor, 2048, partB, 1024, 2048, 4, 1);
    gAdd(seg2(visual_b, vctx_bB), Wb_node, 2048, partF, 64, 2048, 8, 0);
    gLaunch();
    // F2
    rAdd(partB, 131072, 4, 1, nullptr, 0, 0, rel_out, nullptr, nullptr, nullptr);
    rAdd(partF, 8192, 8, 0, nullptr, 0, 0, v_out, nullptr, nullptr, b_node);
    rLaunch();
}